// Round 6
// baseline (175.500 us; speedup 1.0000x reference)
//
#include <hip/hip_runtime.h>

typedef unsigned short u16;
typedef unsigned int u32;
typedef short bf16x8 __attribute__((ext_vector_type(8)));
typedef float f32x4 __attribute__((ext_vector_type(4)));
typedef float f32x8v __attribute__((ext_vector_type(8)));
typedef float f32x16 __attribute__((ext_vector_type(16)));

#define LOG2E 1.44269504f

__device__ __forceinline__ u16 f2b(float f) {
  union { float f; unsigned u; } v; v.f = f;
  unsigned r = v.u + 0x7FFFu + ((v.u >> 16) & 1u);
  return (u16)(r >> 16);
}

__device__ __forceinline__ u32 pk2(float a, float b) {
  union { float f; u32 u; } x, y; x.f = a; y.f = b;
  return ((x.u + 0x8000u) >> 16) | ((y.u + 0x8000u) & 0xFFFF0000u);
}

// single-instruction pack: {lo=bf16(a), hi=bf16(b)}
__device__ __forceinline__ u32 cvtpk(float a, float b) {
  u32 r;
  asm("v_cvt_pk_bf16_f32 %0, %1, %2" : "=v"(r) : "v"(a), "v"(b));
  return r;
}

__device__ __forceinline__ void plswap(u32& x, u32& y) {
#if __has_builtin(__builtin_amdgcn_permlane32_swap)
  typedef int v2i __attribute__((ext_vector_type(2)));
  v2i r = __builtin_amdgcn_permlane32_swap((int)x, (int)y, false, false);
  x = (u32)r[0]; y = (u32)r[1];
#else
  u32 sx = (u32)__shfl_xor((int)x, 32, 64);
  u32 sy = (u32)__shfl_xor((int)y, 32, 64);
  bool hi = (threadIdx.x & 63) >= 32;
  u32 nx = hi ? sy : x;
  u32 ny = hi ? y : sx;
  x = nx; y = ny;
#endif
}

// async global->LDS, 16B per lane; LDS dest is wave-uniform base (HW adds lane*16)
__device__ __forceinline__ void gld16(const void* g, void* l) {
  __builtin_amdgcn_global_load_lds((const __attribute__((address_space(1))) void*)g,
                                   (__attribute__((address_space(3))) void*)l, 16, 0, 0);
}

// ---------------- cast x: fp32 -> bf16, 4 elems/thread ----------------
__global__ __launch_bounds__(256) void k_cast(const float* __restrict__ in, u16* __restrict__ out) {
  int i = blockIdx.x * 256 + threadIdx.x;
  float4 v = ((const float4*)in)[i];
  ushort4 o;
  o.x = f2b(v.x); o.y = f2b(v.y); o.z = f2b(v.z); o.w = f2b(v.w);
  ((ushort4*)out)[i] = o;
}

// ------------- transpose+cast weights: in[R][C] fp32 -> out[C][R] bf16 -------------
__global__ __launch_bounds__(256) void k_transpose(const float* __restrict__ in, u16* __restrict__ out,
                                                   int R, int C) {
  __shared__ float tile[32][33];
  int c0 = blockIdx.x * 32, r0 = blockIdx.y * 32;
  int tx = threadIdx.x, ty = threadIdx.y;
#pragma unroll
  for (int i = 0; i < 32; i += 8)
    tile[ty + i][tx] = in[(size_t)(r0 + ty + i) * C + c0 + tx];
  __syncthreads();
#pragma unroll
  for (int i = 0; i < 32; i += 8)
    out[(size_t)(c0 + ty + i) * R + r0 + tx] = f2b(tile[tx][ty + i]);
}

// ------------- GEMM: C[M][N] fp32 = A[M][K]bf16 * Bt[N][K]bf16^T, 128x128 tile -------------
template<int Nsz, int Ksz>
__global__ __launch_bounds__(256) void k_gemm_bt(const u16* __restrict__ A, const u16* __restrict__ Bt,
                                                 float* __restrict__ C) {
  __shared__ u16 As[128 * 32];
  __shared__ u16 Bs[128 * 32];
  const int tid = threadIdx.x;
  const int l = tid & 63, w = tid >> 6;
  const int wm = w >> 1, wn = w & 1;
  const int m0 = blockIdx.x * 128, n0 = blockIdx.y * 128;
  const int rg = l >> 4, cl = l & 15;
  f32x4 acc[4][4] = {};
  for (int k0 = 0; k0 < Ksz; k0 += 32) {
#pragma unroll
    for (int i = 0; i < 2; i++) {
      int c = tid + i * 256;
      int row = c >> 2, off = c & 3;
      uint4 va = *(const uint4*)(A + (size_t)(m0 + row) * Ksz + k0 + off * 8);
      uint4 vb = *(const uint4*)(Bt + (size_t)(n0 + row) * Ksz + k0 + off * 8);
      unsigned ba = (unsigned)((row * 64 + off * 16) ^ ((row & 7) << 4));
      *(uint4*)((char*)As + ba) = va;
      *(uint4*)((char*)Bs + ba) = vb;
    }
    __syncthreads();
    bf16x8 aF[4], bF[4];
#pragma unroll
    for (int m = 0; m < 4; m++) {
      int row = wm * 64 + m * 16 + cl;
      unsigned ba = (unsigned)((row * 64 + rg * 16) ^ ((row & 7) << 4));
      aF[m] = *(const bf16x8*)((char*)As + ba);
    }
#pragma unroll
    for (int n = 0; n < 4; n++) {
      int row = wn * 64 + n * 16 + cl;
      unsigned ba = (unsigned)((row * 64 + rg * 16) ^ ((row & 7) << 4));
      bF[n] = *(const bf16x8*)((char*)Bs + ba);
    }
#pragma unroll
    for (int m = 0; m < 4; m++)
#pragma unroll
      for (int n = 0; n < 4; n++)
        acc[m][n] = __builtin_amdgcn_mfma_f32_16x16x32_bf16(aF[m], bF[n], acc[m][n], 0, 0, 0);
    __syncthreads();
  }
#pragma unroll
  for (int m = 0; m < 4; m++)
#pragma unroll
    for (int n = 0; n < 4; n++)
#pragma unroll
      for (int r = 0; r < 4; r++)
        C[(size_t)(m0 + wm * 64 + m * 16 + rg * 4 + r) * Nsz + n0 + wn * 64 + n * 16 + cl] = acc[m][n][r];
}

// ------------- RoPE Q/K (vectorized x8); scatter to head-major bf16 (Q scaled by 1/8) -------------
__global__ __launch_bounds__(256) void k_rope(const float* __restrict__ qkv, const float* __restrict__ cs,
                                              const float* __restrict__ sn, u16* __restrict__ Qb,
                                              u16* __restrict__ Kb) {
  int idx = blockIdx.x * 256 + threadIdx.x;  // over 4096*192 8-elem chunks
  int c8 = idx % 192;
  int row = idx / 192;
  int c = c8 * 8;
  int b = row >> 11, t = row & 2047;
  int d = c & 63;
  const float* rp = qkv + (size_t)row * 2048;
  f32x8v x = *(const f32x8v*)(rp + c);
  int po = (d < 32) ? c + 32 : c - 32;
  float sgn = (d < 32) ? -1.f : 1.f;
  f32x8v xr = *(const f32x8v*)(rp + po);
  f32x8v cc = *(const f32x8v*)(cs + t * 64 + d);
  f32x8v ss = *(const f32x8v*)(sn + t * 64 + d);
  f32x8v val = x * cc + (xr * sgn) * ss;
  float scale = (c < 1024) ? 0.125f : 1.0f;
  uint4 ov;
  ov.x = pk2(val[0] * scale, val[1] * scale);
  ov.y = pk2(val[2] * scale, val[3] * scale);
  ov.z = pk2(val[4] * scale, val[5] * scale);
  ov.w = pk2(val[6] * scale, val[7] * scale);
  if (c < 1024) {
    int h = c >> 6;
    *(uint4*)(Qb + ((size_t)(b * 16 + h) * 2048 + t) * 64 + d) = ov;
  } else {
    int kk = (c - 1024) >> 6;
    *(uint4*)(Kb + ((size_t)(b * 8 + kk) * 2048 + t) * 64 + d) = ov;
  }
}

// ------------- V transpose: qkv fp32 V-part -> Vt[b*8+kh][64][2048] bf16 -------------
__global__ __launch_bounds__(256) void k_vtrans(const float* __restrict__ qkv, u16* __restrict__ Vt) {
  __shared__ u16 tile[64][65];
  int blk = blockIdx.x;
  int t0 = (blk & 31) * 64;
  int bh = blk >> 5;  // b*8+kh
  int tx = threadIdx.x & 63, ty = threadIdx.x >> 6;
  const float* src = qkv + (size_t)((bh >> 3) * 2048 + t0) * 2048 + 1536 + (bh & 7) * 64;
#pragma unroll
  for (int i = 0; i < 64; i += 4)
    tile[ty + i][tx] = f2b(src[(size_t)(ty + i) * 2048 + tx]);
  __syncthreads();
  u16* dst = Vt + (size_t)bh * 64 * 2048 + t0;
#pragma unroll
  for (int i = 0; i < 64; i += 4)
    dst[(size_t)(ty + i) * 2048 + tx] = tile[tx][ty + i];
}

// ------------- causal flash attention v6: 8-wave blocks, split-KV in-block, 4 waves/SIMD ----
// block = (b, kh, g): 8 waves = 2 heads x qt in {2g,2g+1} x 2 kv-halves. Per-stream
// double-buffered K/V LDS (64KB) via global_load_lds, swz(row)=(row^(row>>3))&7 kills
// 128B-stride bank conflicts. Halves merged in LDS (overlaying staging buffers).
__global__ __launch_bounds__(512, 4) void k_flash6(const u16* __restrict__ Qb, const u16* __restrict__ Kb,
                                                   const u16* __restrict__ Vt, u16* __restrict__ Ob) {
  __shared__ u16 smem[32768];  // 64KB: K[2 stream][2 buf][4096] + V[...]; overlaid by merge bufs
  const int tid = threadIdx.x;
  const int l = tid & 63, w = tid >> 6;
  const int s = w >> 2;          // kv half
  const int wl = w & 3;          // wave-in-stream (also merge unit id)
  const int bid = blockIdx.x;
  const int bkh = bid & 15, g = 31 - (bid >> 4);   // kh fastest (XCD L2), g descending (LPT)
  const int b = bkh >> 3, kh = bkh & 7;
  const int h = kh * 2 + (w & 1);
  const int qt = 2 * g + ((w >> 1) & 1);
  const int q0 = qt * 32;
  const int lq = l & 31, hi = l >> 5;
  const int q = q0 + lq;
  const int sA = (lq ^ (lq >> 3)) & 7;             // swz of row lq; row+32 -> sA^4

  const int NT = g + 1;
  const int nh0 = (NT + 1) >> 1;
  const int tbeg = s ? nh0 : 0;
  const int cnt = s ? (NT - nh0) : nh0;

  const u16* Kg = Kb + (size_t)(b * 8 + kh) * 2048 * 64;
  const u16* Vg = Vt + (size_t)(b * 8 + kh) * 64 * 2048;
  const u16* Qp = Qb + ((size_t)(b * 16 + h) * 2048 + q) * 64 + hi * 8;

  // staging: each wave covers 8 rows per call (lane l -> row += l>>3, chunk l&7)
#define STAGE(buf, t)                                                                    \
  {                                                                                      \
    const int kvb_ = (t) << 6;                                                           \
    _Pragma("unroll")                                                                    \
    for (int c = 0; c < 2; c++) {                                                        \
      int row = c * 32 + wl * 8 + (l >> 3);                                              \
      int gch = (l & 7) ^ ((row ^ (row >> 3)) & 7);                                      \
      gld16(Kg + (size_t)(kvb_ + row) * 64 + gch * 8,                                    \
            smem + (s * 2 + (buf)) * 4096 + (c * 32 + wl * 8) * 64);                     \
    }                                                                                    \
    _Pragma("unroll")                                                                    \
    for (int c = 0; c < 2; c++) {                                                        \
      int row = c * 32 + wl * 8 + (l >> 3);                                              \
      int gch = (l & 7) ^ ((row ^ (row >> 3)) & 7);                                      \
      gld16(Vg + (size_t)row * 2048 + kvb_ + gch * 8,                                    \
            smem + 16384 + (s * 2 + (buf)) * 4096 + (c * 32 + wl * 8) * 64);             \
    }                                                                                    \
  }

  if (cnt > 0) STAGE(0, tbeg);

  bf16x8 qf[4];
#pragma unroll
  for (int ks = 0; ks < 4; ks++) qf[ks] = *(const bf16x8*)(Qp + ks * 16);

  f32x16 oa[2] = {};
  float m = -3e38f, lsum = 0.f;

  for (int st = 0; st < nh0; st++) {
    const int cur = st & 1;
    if (st + 1 < cnt) {
      STAGE(cur ^ 1, tbeg + st + 1);
      asm volatile("s_waitcnt vmcnt(4)" ::: "memory");
    } else {
      asm volatile("s_waitcnt vmcnt(0)" ::: "memory");
    }
    __builtin_amdgcn_s_barrier();
    asm volatile("" ::: "memory");

    if (st < cnt) {
      const int t = tbeg + st;
      const int kvb = t << 6;
      const u16* KL = smem + (s * 2 + cur) * 4096;
      const u16* VL = smem + 16384 + (s * 2 + cur) * 4096;

      bf16x8 kf0[4], kf1[4];
#pragma unroll
      for (int ks = 0; ks < 4; ks++) {
        int kc = (ks << 1) | hi;
        kf0[ks] = *(const bf16x8*)(KL + lq * 64 + ((kc ^ sA) << 3));
        kf1[ks] = *(const bf16x8*)(KL + (lq + 32) * 64 + ((kc ^ sA ^ 4) << 3));
      }
      f32x16 s0 = {}, s1 = {};
      __builtin_amdgcn_s_setprio(1);
#pragma unroll
      for (int ks = 0; ks < 4; ks++) {
        s0 = __builtin_amdgcn_mfma_f32_32x32x16_bf16(kf0[ks], qf[ks], s0, 0, 0, 0);
        s1 = __builtin_amdgcn_mfma_f32_32x32x16_bf16(kf1[ks], qf[ks], s1, 0, 0, 0);
      }
      __builtin_amdgcn_s_setprio(0);

      // V fragments issued before softmax (LDS latency hides under VALU)
      bf16x8 vf[2][2][2];
#pragma unroll
      for (int dt = 0; dt < 2; dt++)
#pragma unroll
        for (int n = 0; n < 2; n++)
#pragma unroll
          for (int s16 = 0; s16 < 2; s16++) {
            int vc = n * 4 + s16 * 2 + hi;
            int cc = (vc ^ sA ^ (dt ? 4 : 0)) << 3;
            vf[dt][n][s16] = *(const bf16x8*)(VL + (dt * 32 + lq) * 64 + cc);
          }

      // causal mask (global last tile only)
      if (t == NT - 1) {
#pragma unroll
        for (int r = 0; r < 16; r++) {
          int kvr = kvb + (r & 3) + 8 * (r >> 2) + 4 * hi;
          if (kvr > q) s0[r] = -3e38f;
          if (kvr + 32 > q) s1[r] = -3e38f;
        }
      }

      // online softmax; T13 defer-max
      float tr[16];
#pragma unroll
      for (int r = 0; r < 16; r++) tr[r] = fmaxf(s0[r], s1[r]);
#pragma unroll
      for (int i = 0; i < 5; i++) tr[i] = fmaxf(fmaxf(tr[3 * i], tr[3 * i + 1]), tr[3 * i + 2]);
      tr[0] = fmaxf(fmaxf(tr[0], tr[1]), tr[2]);
      tr[0] = fmaxf(fmaxf(tr[0], tr[3]), fmaxf(tr[4], tr[15]));
      float mx = fmaxf(tr[0], __shfl_xor(tr[0], 32, 64));
      bool keep = __all(mx - m <= 8.f);
      float mnew = keep ? m : fmaxf(m, mx);
      float alpha = keep ? 1.f : exp2f((m - mnew) * LOG2E);
      m = mnew;
      float mb = m * LOG2E;
#pragma unroll
      for (int r = 0; r < 16; r++) {
        s0[r] = exp2f(fmaf(s0[r], LOG2E, -mb));
        s1[r] = exp2f(fmaf(s1[r], LOG2E, -mb));
      }
#pragma unroll
      for (int r = 0; r < 16; r++) tr[r] = s0[r] + s1[r];
#pragma unroll
      for (int st2 = 8; st2 >= 1; st2 >>= 1)
#pragma unroll
        for (int i = 0; i < st2; i++) tr[i] += tr[i + st2];
      float ssum = tr[0] + __shfl_xor(tr[0], 32, 64);
      if (!keep) {
        lsum *= alpha;
#pragma unroll
        for (int r = 0; r < 16; r++) { oa[0][r] *= alpha; oa[1][r] *= alpha; }
      }
      lsum += ssum;

      // P -> bf16 B-fragments (cvt_pk + permlane32_swap), then PV: O^T += V^T . P
#pragma unroll
      for (int n = 0; n < 2; n++) {
        u32 aw[8];
#pragma unroll
        for (int j = 0; j < 8; j++) {
          float va = n ? s1[2 * j] : s0[2 * j];
          float vb = n ? s1[2 * j + 1] : s0[2 * j + 1];
          aw[j] = cvtpk(va, vb);
        }
        plswap(aw[0], aw[2]); plswap(aw[1], aw[3]);
        plswap(aw[4], aw[6]); plswap(aw[5], aw[7]);
        union { u32 uu[4]; bf16x8 v; } p0, p1;
#pragma unroll
        for (int j = 0; j < 4; j++) { p0.uu[j] = aw[j]; p1.uu[j] = aw[4 + j]; }
        __builtin_amdgcn_s_setprio(1);
#pragma unroll
        for (int dt = 0; dt < 2; dt++) {
          oa[dt] = __builtin_amdgcn_mfma_f32_32x32x16_bf16(vf[dt][n][0], p0.v, oa[dt], 0, 0, 0);
          oa[dt] = __builtin_amdgcn_mfma_f32_32x32x16_bf16(vf[dt][n][1], p1.v, oa[dt], 0, 0, 0);
        }
        __builtin_amdgcn_s_setprio(0);
      }
    }

    asm volatile("" ::: "memory");
    __builtin_amdgcn_s_barrier();
  }

  // ---- merge the two kv-halves (overlay staging LDS; all staging reads are done) ----
  float* mbuf = (float*)smem;                 // [4][64] stride 33 floats -> 33792 B
  float* mlm = (float*)(smem + 16896);        // [4][2][64] -> 2 KB
  u32* otileB = (u32*)(smem + 17920);         // [4][32*33] -> 16.9 KB (total 51.5 KB < 64 KB)
  __syncthreads();
  if (s) {
    mlm[wl * 128 + l] = m;
    mlm[wl * 128 + 64 + l] = lsum;
    float* mb_ = mbuf + ((size_t)(wl * 64 + l)) * 33;
#pragma unroll
    for (int r = 0; r < 16; r++) {
      mb_[r] = oa[0][r];
      mb_[16 + r] = oa[1][r];
    }
  }
  __syncthreads();
  if (!s) {
    float m1 = mlm[wl * 128 + l], l1 = mlm[wl * 128 + 64 + l];
    float ms = fmaxf(m, m1);
    float a0 = exp2f((m - ms) * LOG2E);
    float a1 = exp2f((m1 - ms) * LOG2E);
    float linv = 1.0f / (lsum * a0 + l1 * a1);
    const float* mb_ = mbuf + ((size_t)(wl * 64 + l)) * 33;
    float of[32];
#pragma unroll
    for (int r = 0; r < 16; r++) {
      of[r] = (oa[0][r] * a0 + mb_[r] * a1) * linv;
      of[16 + r] = (oa[1][r] * a0 + mb_[16 + r] * a1) * linv;
    }
    // transpose O^T -> O via unit-private LDS (stride 33), coalesced store
    u32* ot = otileB + wl * (32 * 33);
#pragma unroll
    for (int dt = 0; dt < 2; dt++)
#pragma unroll
      for (int r = 0; r < 16; r += 2) {
        int d = dt * 32 + (r & 3) + 8 * (r >> 2) + 4 * hi;
        ot[lq * 33 + (d >> 1)] = cvtpk(of[dt * 16 + r], of[dt * 16 + r + 1]);
      }
    const u32* otr = otileB + wl * (32 * 33);
#pragma unroll
    for (int i = 0; i < 16; i++) {
      int wd = i * 64 + l;
      int row = wd >> 5, col = wd & 31;
      u32 v = otr[row * 33 + col];
      *(u32*)(Ob + (size_t)(b * 2048 + q0 + row) * 1024 + h * 64 + col * 2) = v;
    }
  }
#undef STAGE
}

extern "C" void kernel_launch(void* const* d_in, const int* in_sizes, int n_in,
                              void* d_out, int out_size, void* d_ws, size_t ws_size,
                              hipStream_t stream) {
  const float* x = (const float*)d_in[0];
  const float* cs = (const float*)d_in[1];
  const float* sn = (const float*)d_in[2];
  const float* w_qkv = (const float*)d_in[3];
  const float* w_out = (const float*)d_in[4];
  float* out = (float*)d_out;
  char* ws = (char*)d_ws;

  u16* Xb   = (u16*)(ws + (size_t)(0u) );          // 8 MB  [4096][1024]
  u16* Wqt  = (u16*)(ws + ((size_t)8u << 20));     // 4 MB  [2048][1024]
  u16* Wot  = (u16*)(ws + ((size_t)12u << 20));    // 2 MB  [1024][1024]
  float* qkv = (float*)(ws + ((size_t)14u << 20)); // 32 MB [4096][2048]
  u16* Qb   = (u16*)(ws + ((size_t)46u << 20));    // 8 MB  [2][16][2048][64]
  u16* Kb   = (u16*)(ws + ((size_t)54u << 20));    // 4 MB  [2][8][2048][64]
  u16* Vt   = (u16*)(ws + ((size_t)58u << 20));    // 4 MB  [2][8][64][2048]
  u16* Ob   = (u16*)(ws + ((size_t)62u << 20));    // 8 MB  [4096][1024]

  k_cast<<<4096, 256, 0, stream>>>(x, Xb);
  k_transpose<<<dim3(2048 / 32, 1024 / 32), dim3(32, 8), 0, stream>>>(w_qkv, Wqt, 1024, 2048);
  k_transpose<<<dim3(1024 / 32, 1024 / 32), dim3(32, 8), 0, stream>>>(w_out, Wot, 1024, 1024);
  k_gemm_bt<2048, 1024><<<dim3(32, 16), 256, 0, stream>>>(Xb, Wqt, qkv);
  k_rope<<<3072, 256, 0, stream>>>(qkv, cs, sn, Qb, Kb);
  k_vtrans<<<512, 256, 0, stream>>>(qkv, Vt);
  k_flash6<<<512, 512, 0, stream>>>(Qb, Kb, Vt, Ob);
  k_gemm_bt<1024, 1024><<<dim3(32, 8), 256, 0, stream>>>(Ob, Wot, out);
}

// Round 7
// 120.157 us; speedup vs baseline: 1.4606x; 1.4606x over previous
//
#include <hip/hip_runtime.h>

typedef unsigned short u16;
typedef unsigned int u32;
typedef short bf16x8 __attribute__((ext_vector_type(8)));
typedef float f32x4 __attribute__((ext_vector_type(4)));
typedef float f32x8v __attribute__((ext_vector_type(8)));
typedef float f32x16 __attribute__((ext_vector_type(16)));

#define LOG2E 1.44269504f

__device__ __forceinline__ u16 f2b(float f) {
  union { float f; unsigned u; } v; v.f = f;
  unsigned r = v.u + 0x7FFFu + ((v.u >> 16) & 1u);
  return (u16)(r >> 16);
}

__device__ __forceinline__ u32 pk2(float a, float b) {
  union { float f; u32 u; } x, y; x.f = a; y.f = b;
  return ((x.u + 0x8000u) >> 16) | ((y.u + 0x8000u) & 0xFFFF0000u);
}

// single-instruction pack: {lo=bf16(a), hi=bf16(b)}
__device__ __forceinline__ u32 cvtpk(float a, float b) {
  u32 r;
  asm("v_cvt_pk_bf16_f32 %0, %1, %2" : "=v"(r) : "v"(a), "v"(b));
  return r;
}

__device__ __forceinline__ void plswap(u32& x, u32& y) {
#if __has_builtin(__builtin_amdgcn_permlane32_swap)
  typedef int v2i __attribute__((ext_vector_type(2)));
  v2i r = __builtin_amdgcn_permlane32_swap((int)x, (int)y, false, false);
  x = (u32)r[0]; y = (u32)r[1];
#else
  u32 sx = (u32)__shfl_xor((int)x, 32, 64);
  u32 sy = (u32)__shfl_xor((int)y, 32, 64);
  bool hi = (threadIdx.x & 63) >= 32;
  u32 nx = hi ? sy : x;
  u32 ny = hi ? y : sx;
  x = nx; y = ny;
#endif
}

// async global->LDS, 16B per lane; LDS dest is wave-uniform base (HW adds lane*16)
__device__ __forceinline__ void gld16(const void* g, void* l) {
  __builtin_amdgcn_global_load_lds((const __attribute__((address_space(1))) void*)g,
                                   (__attribute__((address_space(3))) void*)l, 16, 0, 0);
}

// ---------------- cast x: fp32 -> bf16, 4 elems/thread ----------------
__global__ __launch_bounds__(256) void k_cast(const float* __restrict__ in, u16* __restrict__ out) {
  int i = blockIdx.x * 256 + threadIdx.x;
  float4 v = ((const float4*)in)[i];
  ushort4 o;
  o.x = f2b(v.x); o.y = f2b(v.y); o.z = f2b(v.z); o.w = f2b(v.w);
  ((ushort4*)out)[i] = o;
}

// ------------- transpose+cast weights: in[R][C] fp32 -> out[C][R] bf16 -------------
__global__ __launch_bounds__(256) void k_transpose(const float* __restrict__ in, u16* __restrict__ out,
                                                   int R, int C) {
  __shared__ float tile[32][33];
  int c0 = blockIdx.x * 32, r0 = blockIdx.y * 32;
  int tx = threadIdx.x, ty = threadIdx.y;
#pragma unroll
  for (int i = 0; i < 32; i += 8)
    tile[ty + i][tx] = in[(size_t)(r0 + ty + i) * C + c0 + tx];
  __syncthreads();
#pragma unroll
  for (int i = 0; i < 32; i += 8)
    out[(size_t)(c0 + ty + i) * R + r0 + tx] = f2b(tile[tx][ty + i]);
}

// ------------- GEMM: C[M][N] fp32 = A[M][K]bf16 * Bt[N][K]bf16^T, 128x128 tile -------------
template<int Nsz, int Ksz>
__global__ __launch_bounds__(256) void k_gemm_bt(const u16* __restrict__ A, const u16* __restrict__ Bt,
                                                 float* __restrict__ C) {
  __shared__ u16 As[128 * 32];
  __shared__ u16 Bs[128 * 32];
  const int tid = threadIdx.x;
  const int l = tid & 63, w = tid >> 6;
  const int wm = w >> 1, wn = w & 1;
  const int m0 = blockIdx.x * 128, n0 = blockIdx.y * 128;
  const int rg = l >> 4, cl = l & 15;
  f32x4 acc[4][4] = {};
  for (int k0 = 0; k0 < Ksz; k0 += 32) {
#pragma unroll
    for (int i = 0; i < 2; i++) {
      int c = tid + i * 256;
      int row = c >> 2, off = c & 3;
      uint4 va = *(const uint4*)(A + (size_t)(m0 + row) * Ksz + k0 + off * 8);
      uint4 vb = *(const uint4*)(Bt + (size_t)(n0 + row) * Ksz + k0 + off * 8);
      unsigned ba = (unsigned)((row * 64 + off * 16) ^ ((row & 7) << 4));
      *(uint4*)((char*)As + ba) = va;
      *(uint4*)((char*)Bs + ba) = vb;
    }
    __syncthreads();
    bf16x8 aF[4], bF[4];
#pragma unroll
    for (int m = 0; m < 4; m++) {
      int row = wm * 64 + m * 16 + cl;
      unsigned ba = (unsigned)((row * 64 + rg * 16) ^ ((row & 7) << 4));
      aF[m] = *(const bf16x8*)((char*)As + ba);
    }
#pragma unroll
    for (int n = 0; n < 4; n++) {
      int row = wn * 64 + n * 16 + cl;
      unsigned ba = (unsigned)((row * 64 + rg * 16) ^ ((row & 7) << 4));
      bF[n] = *(const bf16x8*)((char*)Bs + ba);
    }
#pragma unroll
    for (int m = 0; m < 4; m++)
#pragma unroll
      for (int n = 0; n < 4; n++)
        acc[m][n] = __builtin_amdgcn_mfma_f32_16x16x32_bf16(aF[m], bF[n], acc[m][n], 0, 0, 0);
    __syncthreads();
  }
#pragma unroll
  for (int m = 0; m < 4; m++)
#pragma unroll
    for (int n = 0; n < 4; n++)
#pragma unroll
      for (int r = 0; r < 4; r++)
        C[(size_t)(m0 + wm * 64 + m * 16 + rg * 4 + r) * Nsz + n0 + wn * 64 + n * 16 + cl] = acc[m][n][r];
}

// ------------- RoPE Q/K (vectorized x8); scatter to head-major bf16 (Q scaled by 1/8) -------------
__global__ __launch_bounds__(256) void k_rope(const float* __restrict__ qkv, const float* __restrict__ cs,
                                              const float* __restrict__ sn, u16* __restrict__ Qb,
                                              u16* __restrict__ Kb) {
  int idx = blockIdx.x * 256 + threadIdx.x;  // over 4096*192 8-elem chunks
  int c8 = idx % 192;
  int row = idx / 192;
  int c = c8 * 8;
  int b = row >> 11, t = row & 2047;
  int d = c & 63;
  const float* rp = qkv + (size_t)row * 2048;
  f32x8v x = *(const f32x8v*)(rp + c);
  int po = (d < 32) ? c + 32 : c - 32;
  float sgn = (d < 32) ? -1.f : 1.f;
  f32x8v xr = *(const f32x8v*)(rp + po);
  f32x8v cc = *(const f32x8v*)(cs + t * 64 + d);
  f32x8v ss = *(const f32x8v*)(sn + t * 64 + d);
  f32x8v val = x * cc + (xr * sgn) * ss;
  float scale = (c < 1024) ? 0.125f : 1.0f;
  uint4 ov;
  ov.x = pk2(val[0] * scale, val[1] * scale);
  ov.y = pk2(val[2] * scale, val[3] * scale);
  ov.z = pk2(val[4] * scale, val[5] * scale);
  ov.w = pk2(val[6] * scale, val[7] * scale);
  if (c < 1024) {
    int h = c >> 6;
    *(uint4*)(Qb + ((size_t)(b * 16 + h) * 2048 + t) * 64 + d) = ov;
  } else {
    int kk = (c - 1024) >> 6;
    *(uint4*)(Kb + ((size_t)(b * 8 + kk) * 2048 + t) * 64 + d) = ov;
  }
}

// ------------- V transpose: qkv fp32 V-part -> Vt[b*8+kh][64][2048] bf16 -------------
__global__ __launch_bounds__(256) void k_vtrans(const float* __restrict__ qkv, u16* __restrict__ Vt) {
  __shared__ u16 tile[64][65];
  int blk = blockIdx.x;
  int t0 = (blk & 31) * 64;
  int bh = blk >> 5;  // b*8+kh
  int tx = threadIdx.x & 63, ty = threadIdx.x >> 6;
  const float* src = qkv + (size_t)((bh >> 3) * 2048 + t0) * 2048 + 1536 + (bh & 7) * 64;
#pragma unroll
  for (int i = 0; i < 64; i += 4)
    tile[ty + i][tx] = f2b(src[(size_t)(ty + i) * 2048 + tx]);
  __syncthreads();
  u16* dst = Vt + (size_t)bh * 64 * 2048 + t0;
#pragma unroll
  for (int i = 0; i < 64; i += 4)
    dst[(size_t)(ty + i) * 2048 + tx] = tile[tx][ty + i];
}

// ---- causal flash attention v7: block=(b,kh,qt), 8 waves = 2 heads x 4 kv-streams ----
// KVBLK=32/stream (small state, no spills). Stream s computes tiles {s, s+4, ...};
// K/V double-buffered LDS per stream via global_load_lds with inverse-swizzled source
// (K: ch^(row&7) on 128B rows; V^T: ch^((d>>1)&3) on 64B rows -> conflict-free reads).
// 4-way merge per head in LDS epilogue (overlays staging buffers).
__global__ __launch_bounds__(512, 4) void k_flash7(const u16* __restrict__ Qb, const u16* __restrict__ Kb,
                                                   const u16* __restrict__ Vt, u16* __restrict__ Ob) {
  __shared__ u16 smem[32768];  // 64KB: 4 streams x [K dbuf 2x4KB | V dbuf 2x4KB]
  const int tid = threadIdx.x;
  const int l = tid & 63, w = tid >> 6;
  const int sid = w >> 1;        // kv stream 0..3
  const int h01 = w & 1;         // head within kh
  const int bid = blockIdx.x;
  const int bkh = bid & 15, qt = 63 - (bid >> 4);  // kh fastest (XCD L2), qt descending (LPT)
  const int b = bkh >> 3, kh = bkh & 7;
  const int h = kh * 2 + h01;
  const int q0 = qt * 32;
  const int lq = l & 31, hi = l >> 5;
  const int q = q0 + lq;

  const int cnt = (qt + 4 - sid) >> 2;   // tiles for this stream (t = sid + 4i), 0 allowed
  const int CNTMAX = (qt >> 2) + 1;

  const u16* Kg = Kb + (size_t)(b * 8 + kh) * 2048 * 64;
  const u16* Vg = Vt + (size_t)(b * 8 + kh) * 64 * 2048;
  const u16* Qp = Qb + ((size_t)(b * 16 + h) * 2048 + q) * 64 + hi * 8;

  const int su = sid * 8192;     // u16 units: 16KB per stream
  const int krow_l = l >> 3;     // staging lane decode (K: 8 rows x 8 chunks / call)
  const int kch_l = l & 7;
  const int vrow_l = l >> 2;     // (V: 16 rows x 4 chunks / call)
  const int vch_l = l & 3;

#define STAGE(buf, t)                                                               \
  {                                                                                 \
    const int kvb_ = (t) << 5;                                                      \
    _Pragma("unroll")                                                               \
    for (int c = 0; c < 2; c++) {                                                   \
      int br = h01 * 16 + c * 8;                                                    \
      int row = br + krow_l;                                                        \
      gld16(Kg + (size_t)(kvb_ + row) * 64 + ((kch_l ^ (row & 7)) << 3),            \
            smem + su + (buf) * 2048 + br * 64);                                    \
    }                                                                               \
    _Pragma("unroll")                                                               \
    for (int c = 0; c < 2; c++) {                                                   \
      int bd = h01 * 32 + c * 16;                                                   \
      int d = bd + vrow_l;                                                          \
      gld16(Vg + (size_t)d * 2048 + kvb_ + ((vch_l ^ ((d >> 1) & 3)) << 3),         \
            smem + su + 4096 + (buf) * 2048 + bd * 32);                             \
    }                                                                               \
  }

  if (cnt > 0) STAGE(0, sid);

  bf16x8 qf[4];
#pragma unroll
  for (int ks = 0; ks < 4; ks++) qf[ks] = *(const bf16x8*)(Qp + ks * 16);

  f32x16 oa[2] = {};
  float m = -3e38f, lsum = 0.f;
  const int vswz = (lq >> 1) & 3;

  for (int i = 0; i < CNTMAX; i++) {
    const int cur = i & 1;
    if (i + 1 < cnt) {
      STAGE(cur ^ 1, sid + 4 * (i + 1));
      asm volatile("s_waitcnt vmcnt(4)" ::: "memory");
    } else {
      asm volatile("s_waitcnt vmcnt(0)" ::: "memory");
    }
    __builtin_amdgcn_s_barrier();
    asm volatile("" ::: "memory");

    if (i < cnt) {
      const int t = sid + 4 * i;
      const u16* KL = smem + su + cur * 2048;
      const u16* VL = smem + su + 4096 + cur * 2048;

      // QK^T: S^T[32kv][32q] = K(32x64) . Q^T, 4 MFMA over d
      bf16x8 kf[4];
#pragma unroll
      for (int ks = 0; ks < 4; ks++) {
        int ch = (ks << 1) | hi;
        kf[ks] = *(const bf16x8*)(KL + lq * 64 + ((ch ^ (lq & 7)) << 3));
      }
      f32x16 s0 = {};
      __builtin_amdgcn_s_setprio(1);
#pragma unroll
      for (int ks = 0; ks < 4; ks++)
        s0 = __builtin_amdgcn_mfma_f32_32x32x16_bf16(kf[ks], qf[ks], s0, 0, 0, 0);
      __builtin_amdgcn_s_setprio(0);

      // V^T fragments (LDS latency hides under softmax VALU)
      bf16x8 vf[2][2];
#pragma unroll
      for (int dt = 0; dt < 2; dt++)
#pragma unroll
        for (int p = 0; p < 2; p++) {
          int ch = (p << 1) | hi;
          vf[dt][p] = *(const bf16x8*)(VL + (dt * 32 + lq) * 32 + ((ch ^ vswz) << 3));
        }

      // causal mask (diagonal tile only: t == qt)
      if (t == qt) {
#pragma unroll
        for (int r = 0; r < 16; r++) {
          int kvr = (t << 5) + (r & 3) + 8 * (r >> 2) + 4 * hi;
          if (kvr > q) s0[r] = -3e38f;
        }
      }

      // online softmax over 32 kv (16 here + 16 in partner lane l^32); T13 defer-max
      float tr[16];
#pragma unroll
      for (int r = 0; r < 16; r++) tr[r] = s0[r];
#pragma unroll
      for (int st = 8; st >= 1; st >>= 1)
#pragma unroll
        for (int j = 0; j < st; j++) tr[j] = fmaxf(tr[j], tr[j + st]);
      float mx = fmaxf(tr[0], __shfl_xor(tr[0], 32, 64));
      bool keep = __all(mx - m <= 8.f);
      float mnew = keep ? m : fmaxf(m, mx);
      float alpha = keep ? 1.f : exp2f((m - mnew) * LOG2E);
      m = mnew;
      float mb = m * LOG2E;
#pragma unroll
      for (int r = 0; r < 16; r++) s0[r] = exp2f(fmaf(s0[r], LOG2E, -mb));
#pragma unroll
      for (int r = 0; r < 16; r++) tr[r] = s0[r];
#pragma unroll
      for (int st = 8; st >= 1; st >>= 1)
#pragma unroll
        for (int j = 0; j < st; j++) tr[j] += tr[j + st];
      float ssum = tr[0] + __shfl_xor(tr[0], 32, 64);
      if (!keep) {
        lsum *= alpha;
#pragma unroll
        for (int r = 0; r < 16; r++) { oa[0][r] *= alpha; oa[1][r] *= alpha; }
      }
      lsum += ssum;

      // P -> bf16 B-fragments (cvt_pk + permlane32_swap); PV: O^T += V^T . P
      u32 aw[8];
#pragma unroll
      for (int j = 0; j < 8; j++) aw[j] = cvtpk(s0[2 * j], s0[2 * j + 1]);
      plswap(aw[0], aw[2]); plswap(aw[1], aw[3]);
      plswap(aw[4], aw[6]); plswap(aw[5], aw[7]);
      union { u32 uu[4]; bf16x8 v; } p0, p1;
#pragma unroll
      for (int j = 0; j < 4; j++) { p0.uu[j] = aw[j]; p1.uu[j] = aw[4 + j]; }
      __builtin_amdgcn_s_setprio(1);
#pragma unroll
      for (int dt = 0; dt < 2; dt++) {
        oa[dt] = __builtin_amdgcn_mfma_f32_32x32x16_bf16(vf[dt][0], p0.v, oa[dt], 0, 0, 0);
        oa[dt] = __builtin_amdgcn_mfma_f32_32x32x16_bf16(vf[dt][1], p1.v, oa[dt], 0, 0, 0);
      }
      __builtin_amdgcn_s_setprio(0);
    }

    asm volatile("" ::: "memory");
    __builtin_amdgcn_s_barrier();
  }

  // ---- 4-way merge per head (overlay staging LDS) ----
  __syncthreads();
  float* pbuf = (float*)smem;                       // 6 units x 64 lanes x 33 f32 = 50688 B
  float* mlb = (float*)((char*)smem + 50688);       // 6 units x 128 f32 = 3072 B
  if (sid != 0) {
    int uidx = (sid - 1) * 2 + h01;
    float* pb = pbuf + uidx * (64 * 33) + l * 33;
#pragma unroll
    for (int r = 0; r < 16; r++) { pb[r] = oa[0][r]; pb[16 + r] = oa[1][r]; }
    mlb[uidx * 128 + l] = m;
    mlb[uidx * 128 + 64 + l] = lsum;
  }
  __syncthreads();
  if (sid == 0) {
    float ms = m;
#pragma unroll
    for (int s2 = 0; s2 < 3; s2++) ms = fmaxf(ms, mlb[(s2 * 2 + h01) * 128 + l]);
    float a0 = exp2f((m - ms) * LOG2E);
    float ltot = lsum * a0;
    float of[32];
#pragma unroll
    for (int r = 0; r < 16; r++) { of[r] = oa[0][r] * a0; of[16 + r] = oa[1][r] * a0; }
#pragma unroll
    for (int s2 = 0; s2 < 3; s2++) {
      int uidx = s2 * 2 + h01;
      float a1 = exp2f((mlb[uidx * 128 + l] - ms) * LOG2E);
      ltot += mlb[uidx * 128 + 64 + l] * a1;
      const float* pb = pbuf + uidx * (64 * 33) + l * 33;
#pragma unroll
      for (int r = 0; r < 16; r++) { of[r] += pb[r] * a1; of[16 + r] += pb[16 + r] * a1; }
    }
    float linv = 1.0f / ltot;
    // transpose O^T -> O via head-private LDS tile (stride 33), coalesced store
    u32* ot = (u32*)((char*)smem + 53760) + h01 * (32 * 33);
#pragma unroll
    for (int dt = 0; dt < 2; dt++)
#pragma unroll
      for (int r = 0; r < 16; r += 2) {
        int d = dt * 32 + (r & 3) + 8 * (r >> 2) + 4 * hi;
        ot[lq * 33 + (d >> 1)] = cvtpk(of[dt * 16 + r] * linv, of[dt * 16 + r + 1] * linv);
      }
#pragma unroll
    for (int i2 = 0; i2 < 16; i2++) {
      int wd = i2 * 64 + l;
      int row = wd >> 5, col = wd & 31;
      u32 v = ot[row * 33 + col];
      *(u32*)(Ob + (size_t)(b * 2048 + q0 + row) * 1024 + h * 64 + col * 2) = v;
    }
  }
#undef STAGE
}

extern "C" void kernel_launch(void* const* d_in, const int* in_sizes, int n_in,
                              void* d_out, int out_size, void* d_ws, size_t ws_size,
                              hipStream_t stream) {
  const float* x = (const float*)d_in[0];
  const float* cs = (const float*)d_in[1];
  const float* sn = (const float*)d_in[2];
  const float* w_qkv = (const float*)d_in[3];
  const float* w_out = (const float*)d_in[4];
  float* out = (float*)d_out;
  char* ws = (char*)d_ws;

  u16* Xb   = (u16*)(ws + (size_t)(0u) );          // 8 MB  [4096][1024]
  u16* Wqt  = (u16*)(ws + ((size_t)8u << 20));     // 4 MB  [2048][1024]
  u16* Wot  = (u16*)(ws + ((size_t)12u << 20));    // 2 MB  [1024][1024]
  float* qkv = (float*)(ws + ((size_t)14u << 20)); // 32 MB [4096][2048]
  u16* Qb   = (u16*)(ws + ((size_t)46u << 20));    // 8 MB  [2][16][2048][64]
  u16* Kb   = (u16*)(ws + ((size_t)54u << 20));    // 4 MB  [2][8][2048][64]
  u16* Vt   = (u16*)(ws + ((size_t)58u << 20));    // 4 MB  [2][8][64][2048]
  u16* Ob   = (u16*)(ws + ((size_t)62u << 20));    // 8 MB  [4096][1024]

  k_cast<<<4096, 256, 0, stream>>>(x, Xb);
  k_transpose<<<dim3(2048 / 32, 1024 / 32), dim3(32, 8), 0, stream>>>(w_qkv, Wqt, 1024, 2048);
  k_transpose<<<dim3(1024 / 32, 1024 / 32), dim3(32, 8), 0, stream>>>(w_out, Wot, 1024, 1024);
  k_gemm_bt<2048, 1024><<<dim3(32, 16), 256, 0, stream>>>(Xb, Wqt, qkv);
  k_rope<<<3072, 256, 0, stream>>>(qkv, cs, sn, Qb, Kb);
  k_vtrans<<<512, 256, 0, stream>>>(qkv, Vt);
  k_flash7<<<1024, 512, 0, stream>>>(Qb, Kb, Vt, Ob);
  k_gemm_bt<1024, 1024><<<dim3(32, 8), 256, 0, stream>>>(Ob, Wot, out);
}

// Round 8
// 111.530 us; speedup vs baseline: 1.5736x; 1.0774x over previous
//
#include <hip/hip_runtime.h>

typedef unsigned short u16;
typedef unsigned int u32;
typedef short bf16x8 __attribute__((ext_vector_type(8)));
typedef float f32x4 __attribute__((ext_vector_type(4)));
typedef float f32x8v __attribute__((ext_vector_type(8)));
typedef float f32x16 __attribute__((ext_vector_type(16)));

#define LOG2E 1.44269504f

__device__ __forceinline__ u16 f2b(float f) {
  union { float f; unsigned u; } v; v.f = f;
  unsigned r = v.u + 0x7FFFu + ((v.u >> 16) & 1u);
  return (u16)(r >> 16);
}

__device__ __forceinline__ u32 pk2(float a, float b) {
  union { float f; u32 u; } x, y; x.f = a; y.f = b;
  return ((x.u + 0x8000u) >> 16) | ((y.u + 0x8000u) & 0xFFFF0000u);
}

// single-instruction pack: {lo=bf16(a), hi=bf16(b)}
__device__ __forceinline__ u32 cvtpk(float a, float b) {
  u32 r;
  asm("v_cvt_pk_bf16_f32 %0, %1, %2" : "=v"(r) : "v"(a), "v"(b));
  return r;
}

__device__ __forceinline__ float max3f(float a, float b, float c) {
  float r;
  asm("v_max3_f32 %0, %1, %2, %3" : "=v"(r) : "v"(a), "v"(b), "v"(c));
  return r;
}

__device__ __forceinline__ void plswap(u32& x, u32& y) {
#if __has_builtin(__builtin_amdgcn_permlane32_swap)
  typedef int v2i __attribute__((ext_vector_type(2)));
  v2i r = __builtin_amdgcn_permlane32_swap((int)x, (int)y, false, false);
  x = (u32)r[0]; y = (u32)r[1];
#else
  u32 sx = (u32)__shfl_xor((int)x, 32, 64);
  u32 sy = (u32)__shfl_xor((int)y, 32, 64);
  bool hi = (threadIdx.x & 63) >= 32;
  u32 nx = hi ? sy : x;
  u32 ny = hi ? y : sx;
  x = nx; y = ny;
#endif
}

// async global->LDS, 16B per lane; LDS dest is wave-uniform base (HW adds lane*16)
__device__ __forceinline__ void gld16(const void* g, void* l) {
  __builtin_amdgcn_global_load_lds((const __attribute__((address_space(1))) void*)g,
                                   (__attribute__((address_space(3))) void*)l, 16, 0, 0);
}

// ------------- prep0: cast x (blk<4096) | transpose w_qkv (<6144) | transpose w_out -------------
__global__ __launch_bounds__(256) void k_prep0(const float* __restrict__ x, u16* __restrict__ Xb,
                                               const float* __restrict__ w_qkv, u16* __restrict__ Wqt,
                                               const float* __restrict__ w_out, u16* __restrict__ Wot) {
  __shared__ float tile[32][33];
  int blk = blockIdx.x;
  int tid = threadIdx.x;
  if (blk < 4096) {
    int i = blk * 256 + tid;
    float4 v = ((const float4*)x)[i];
    ushort4 o;
    o.x = f2b(v.x); o.y = f2b(v.y); o.z = f2b(v.z); o.w = f2b(v.w);
    ((ushort4*)Xb)[i] = o;
    return;
  }
  const float* in; u16* out; int R, C, t;
  if (blk < 6144) { t = blk - 4096; in = w_qkv; out = Wqt; R = 1024; C = 2048; }
  else            { t = blk - 6144; in = w_out; out = Wot; R = 1024; C = 1024; }
  int nbx = C >> 5;
  int c0 = (t % nbx) * 32, r0 = (t / nbx) * 32;
  int tx = tid & 31, ty = tid >> 5;
#pragma unroll
  for (int i = 0; i < 32; i += 8)
    tile[ty + i][tx] = in[(size_t)(r0 + ty + i) * C + c0 + tx];
  __syncthreads();
#pragma unroll
  for (int i = 0; i < 32; i += 8)
    out[(size_t)(c0 + ty + i) * R + r0 + tx] = f2b(tile[tx][ty + i]);
}

// ------------- GEMM: C[M][N] fp32 = A[M][K]bf16 * Bt[N][K]bf16^T, 128x128 tile -------------
template<int Nsz, int Ksz>
__global__ __launch_bounds__(256) void k_gemm_bt(const u16* __restrict__ A, const u16* __restrict__ Bt,
                                                 float* __restrict__ C) {
  __shared__ u16 As[128 * 32];
  __shared__ u16 Bs[128 * 32];
  const int tid = threadIdx.x;
  const int l = tid & 63, w = tid >> 6;
  const int wm = w >> 1, wn = w & 1;
  const int m0 = blockIdx.x * 128, n0 = blockIdx.y * 128;
  const int rg = l >> 4, cl = l & 15;
  f32x4 acc[4][4] = {};
  for (int k0 = 0; k0 < Ksz; k0 += 32) {
#pragma unroll
    for (int i = 0; i < 2; i++) {
      int c = tid + i * 256;
      int row = c >> 2, off = c & 3;
      uint4 va = *(const uint4*)(A + (size_t)(m0 + row) * Ksz + k0 + off * 8);
      uint4 vb = *(const uint4*)(Bt + (size_t)(n0 + row) * Ksz + k0 + off * 8);
      unsigned ba = (unsigned)((row * 64 + off * 16) ^ ((row & 7) << 4));
      *(uint4*)((char*)As + ba) = va;
      *(uint4*)((char*)Bs + ba) = vb;
    }
    __syncthreads();
    bf16x8 aF[4], bF[4];
#pragma unroll
    for (int m = 0; m < 4; m++) {
      int row = wm * 64 + m * 16 + cl;
      unsigned ba = (unsigned)((row * 64 + rg * 16) ^ ((row & 7) << 4));
      aF[m] = *(const bf16x8*)((char*)As + ba);
    }
#pragma unroll
    for (int n = 0; n < 4; n++) {
      int row = wn * 64 + n * 16 + cl;
      unsigned ba = (unsigned)((row * 64 + rg * 16) ^ ((row & 7) << 4));
      bF[n] = *(const bf16x8*)((char*)Bs + ba);
    }
#pragma unroll
    for (int m = 0; m < 4; m++)
#pragma unroll
      for (int n = 0; n < 4; n++)
        acc[m][n] = __builtin_amdgcn_mfma_f32_16x16x32_bf16(aF[m], bF[n], acc[m][n], 0, 0, 0);
    __syncthreads();
  }
#pragma unroll
  for (int m = 0; m < 4; m++)
#pragma unroll
    for (int n = 0; n < 4; n++)
#pragma unroll
      for (int r = 0; r < 4; r++)
        C[(size_t)(m0 + wm * 64 + m * 16 + rg * 4 + r) * Nsz + n0 + wn * 64 + n * 16 + cl] = acc[m][n][r];
}

// ------------- prep1: rope (blk<3072) | V transpose (blk>=3072) -------------
__global__ __launch_bounds__(256) void k_prep1(const float* __restrict__ qkv, const float* __restrict__ cs,
                                               const float* __restrict__ sn, u16* __restrict__ Qb,
                                               u16* __restrict__ Kb, u16* __restrict__ Vt) {
  __shared__ u16 tile[64][65];
  int blk = blockIdx.x;
  int tid = threadIdx.x;
  if (blk < 3072) {
    int idx = blk * 256 + tid;  // over 4096*192 8-elem chunks
    int c8 = idx % 192;
    int row = idx / 192;
    int c = c8 * 8;
    int b = row >> 11, t = row & 2047;
    int d = c & 63;
    const float* rp = qkv + (size_t)row * 2048;
    f32x8v x = *(const f32x8v*)(rp + c);
    int po = (d < 32) ? c + 32 : c - 32;
    float sgn = (d < 32) ? -1.f : 1.f;
    f32x8v xr = *(const f32x8v*)(rp + po);
    f32x8v cc = *(const f32x8v*)(cs + t * 64 + d);
    f32x8v ss = *(const f32x8v*)(sn + t * 64 + d);
    f32x8v val = x * cc + (xr * sgn) * ss;
    float scale = (c < 1024) ? 0.125f : 1.0f;
    uint4 ov;
    ov.x = pk2(val[0] * scale, val[1] * scale);
    ov.y = pk2(val[2] * scale, val[3] * scale);
    ov.z = pk2(val[4] * scale, val[5] * scale);
    ov.w = pk2(val[6] * scale, val[7] * scale);
    if (c < 1024) {
      int h = c >> 6;
      *(uint4*)(Qb + ((size_t)(b * 16 + h) * 2048 + t) * 64 + d) = ov;
    } else {
      int kk = (c - 1024) >> 6;
      *(uint4*)(Kb + ((size_t)(b * 8 + kk) * 2048 + t) * 64 + d) = ov;
    }
    return;
  }
  int vb = blk - 3072;
  int t0 = (vb & 31) * 64;
  int bh = vb >> 5;  // b*8+kh
  int tx = tid & 63, ty = tid >> 6;
  const float* src = qkv + (size_t)((bh >> 3) * 2048 + t0) * 2048 + 1536 + (bh & 7) * 64;
#pragma unroll
  for (int i = 0; i < 64; i += 4)
    tile[ty + i][tx] = f2b(src[(size_t)(ty + i) * 2048 + tx]);
  __syncthreads();
  u16* dst = Vt + (size_t)bh * 64 * 2048 + t0;
#pragma unroll
  for (int i = 0; i < 64; i += 4)
    dst[(size_t)(ty + i) * 2048 + tx] = tile[tx][ty + i];
}

// ---- causal flash attention v8: block=(b,kh,qt), 4 waves = 2 heads x 2 kv-streams ----
// KVBLK=32/stream, stream s owns tiles {s, s+2, ...}. Hoisted staging pointers (const
// stride increments), lsum accumulated by ones-MFMA (no sum tree), shfl-free defer-max,
// max3 reduce. 32KB LDS -> 4 blocks/CU. 2-way merge in LDS epilogue (overlay).
__global__ __launch_bounds__(256, 4) void k_flash8(const u16* __restrict__ Qb, const u16* __restrict__ Kb,
                                                   const u16* __restrict__ Vt, u16* __restrict__ Ob) {
  __shared__ u16 smem[16384];  // 32KB: 2 streams x [K dbuf 2x4KB | V dbuf 2x4KB]
  const int tid = threadIdx.x;
  const int l = tid & 63, w = tid >> 6;
  const int sid = w >> 1;        // kv stream 0..1
  const int h01 = w & 1;         // head within kh
  const int bid = blockIdx.x;
  const int bkh = bid & 15, qt = 63 - (bid >> 4);  // kh fastest (XCD L2), qt descending (LPT)
  const int b = bkh >> 3, kh = bkh & 7;
  const int h = kh * 2 + h01;
  const int q0 = qt * 32;
  const int lq = l & 31, hi = l >> 5;
  const int q = q0 + lq;

  const int cnt = (qt + 2 - sid) >> 1;   // tiles for this stream (t = sid + 2i)
  const int CNTMAX = (qt + 2) >> 1;

  const u16* Kg = Kb + (size_t)(b * 8 + kh) * 2048 * 64;
  const u16* Vg = Vt + (size_t)(b * 8 + kh) * 64 * 2048;
  const u16* Qp = Qb + ((size_t)(b * 16 + h) * 2048 + q) * 64 + hi * 8;

  // ---- hoisted staging pointers (swizzle is tile-invariant; advance by const stride) ----
  const int krow = h01 * 16 + (l >> 3);                 // K row (call c adds +8)
  const u16* kS = Kg + (size_t)(sid * 32 + krow) * 64 + (((l & 7) ^ (krow & 7)) << 3);
  const int vd = h01 * 32 + (l >> 2);                   // V d-row (call c adds +16)
  const u16* vS0 = Vg + (size_t)vd * 2048 + sid * 32 + (((l & 3) ^ ((vd >> 1) & 3)) << 3);
  const u16* vS1 = vS0 + (size_t)16 * 2048;
  char* smB = (char*)smem;
  const int kDst = sid * 16384 + h01 * 2048;            // + buf*4096 (+1024 for call c=1)
  const int vDst = sid * 16384 + 8192 + h01 * 2048;

#define STAGE(buf)                                         \
  {                                                        \
    gld16(kS, smB + kDst + (buf) * 4096);                  \
    gld16(kS + 8 * 64, smB + kDst + (buf) * 4096 + 1024);  \
    gld16(vS0, smB + vDst + (buf) * 4096);                 \
    gld16(vS1, smB + vDst + (buf) * 4096 + 1024);          \
    kS += 2 * 32 * 64; vS0 += 64; vS1 += 64;               \
  }

  if (cnt > 0) STAGE(0);

  bf16x8 qf[4];
#pragma unroll
  for (int ks = 0; ks < 4; ks++) qf[ks] = *(const bf16x8*)(Qp + ks * 16);

  union { u32 uu[4]; bf16x8 v; } ones;
#pragma unroll
  for (int j = 0; j < 4; j++) ones.uu[j] = 0x3F803F80u;

  f32x16 oa[2] = {};
  f32x16 lacc = {};              // lsum accumulator (reg 0 is the live one)
  float m = -3e38f;

  for (int i = 0; i < CNTMAX; i++) {
    const int cur = i & 1;
    if (i + 1 < cnt) {
      STAGE(cur ^ 1);
      asm volatile("s_waitcnt vmcnt(4)" ::: "memory");
    } else {
      asm volatile("s_waitcnt vmcnt(0)" ::: "memory");
    }
    __builtin_amdgcn_s_barrier();
    asm volatile("" ::: "memory");

    if (i < cnt) {
      const int t = sid + 2 * i;
      const char* KL = smB + sid * 16384 + cur * 4096;
      const char* VL = smB + sid * 16384 + 8192 + cur * 4096;

      // QK^T: S^T[32kv][32q] = K(32x64) . Q^T
      bf16x8 kf[4];
#pragma unroll
      for (int ks = 0; ks < 4; ks++)
        kf[ks] = *(const bf16x8*)(KL + lq * 128 + (((ks << 1) | hi) ^ (lq & 7)) * 16);
      f32x16 s0 = {};
      __builtin_amdgcn_s_setprio(1);
#pragma unroll
      for (int ks = 0; ks < 4; ks++)
        s0 = __builtin_amdgcn_mfma_f32_32x32x16_bf16(kf[ks], qf[ks], s0, 0, 0, 0);
      __builtin_amdgcn_s_setprio(0);

      // causal mask (diagonal tile only: t == qt)
      if (t == qt) {
#pragma unroll
        for (int r = 0; r < 16; r++) {
          int kvr = (t << 5) + (r & 3) + 8 * (r >> 2) + 4 * hi;
          if (kvr > q) s0[r] = -3e38f;
        }
      }

      // shfl-free defer-max: __all over 64 lanes covers the hi/lo partner implicitly
      float a5[5];
#pragma unroll
      for (int j = 0; j < 5; j++) a5[j] = max3f(s0[3 * j], s0[3 * j + 1], s0[3 * j + 2]);
      float mx16 = fmaxf(max3f(a5[0], a5[1], a5[2]), max3f(a5[3], a5[4], s0[15]));
      bool keep = __all(mx16 - m <= 8.f);
      if (!keep) {
        float mx = fmaxf(mx16, __shfl_xor(mx16, 32, 64));
        float mnew = fmaxf(m, mx);
        float alpha = exp2f((m - mnew) * LOG2E);
        m = mnew;
        lacc[0] *= alpha;
#pragma unroll
        for (int r = 0; r < 16; r++) { oa[0][r] *= alpha; oa[1][r] *= alpha; }
      }
      float mb = m * LOG2E;
#pragma unroll
      for (int r = 0; r < 16; r++) s0[r] = exp2f(fmaf(s0[r], LOG2E, -mb));

      // P -> bf16 B-fragments (cvt_pk + permlane32_swap)
      u32 aw[8];
#pragma unroll
      for (int j = 0; j < 8; j++) aw[j] = cvtpk(s0[2 * j], s0[2 * j + 1]);
      plswap(aw[0], aw[2]); plswap(aw[1], aw[3]);
      plswap(aw[4], aw[6]); plswap(aw[5], aw[7]);
      union { u32 uu[4]; bf16x8 v; } p0, p1;
#pragma unroll
      for (int j = 0; j < 4; j++) { p0.uu[j] = aw[j]; p1.uu[j] = aw[4 + j]; }

      // V^T fragments (loaded late to cap live VGPRs)
      bf16x8 vf[2][2];
#pragma unroll
      for (int dt = 0; dt < 2; dt++)
#pragma unroll
        for (int p = 0; p < 2; p++)
          vf[dt][p] = *(const bf16x8*)(VL + (dt * 32 + lq) * 64 +
                                       ((((p << 1) | hi) ^ ((lq >> 1) & 3)) << 4));

      // PV: O^T += V^T . P ; lsum += ones . P (row 0 of lacc)
      __builtin_amdgcn_s_setprio(1);
#pragma unroll
      for (int dt = 0; dt < 2; dt++) {
        oa[dt] = __builtin_amdgcn_mfma_f32_32x32x16_bf16(vf[dt][0], p0.v, oa[dt], 0, 0, 0);
        oa[dt] = __builtin_amdgcn_mfma_f32_32x32x16_bf16(vf[dt][1], p1.v, oa[dt], 0, 0, 0);
      }
      lacc = __builtin_amdgcn_mfma_f32_32x32x16_bf16(ones.v, p0.v, lacc, 0, 0, 0);
      lacc = __builtin_amdgcn_mfma_f32_32x32x16_bf16(ones.v, p1.v, lacc, 0, 0, 0);
      __builtin_amdgcn_s_setprio(0);
    }

    asm volatile("" ::: "memory");
    __builtin_amdgcn_s_barrier();
  }

  float lsum = lacc[0];

  // ---- 2-way merge per head (overlay staging LDS) ----
  __syncthreads();
  float* pbuf = (float*)smem;                       // [2][64][33] f32 = 16896 B
  float* mlb = (float*)((char*)smem + 16896);       // [2][128] f32 = 1024 B
  u32* otileB = (u32*)((char*)smem + 17920);        // [2][32*33] u32 = 8448 B
  if (sid == 1) {
    float* pb = pbuf + (h01 * 64 + l) * 33;
#pragma unroll
    for (int r = 0; r < 16; r++) { pb[r] = oa[0][r]; pb[16 + r] = oa[1][r]; }
    mlb[h01 * 128 + l] = m;
    mlb[h01 * 128 + 64 + l] = lsum;
  }
  __syncthreads();
  if (sid == 0) {
    float m1 = mlb[h01 * 128 + l], l1 = mlb[h01 * 128 + 64 + l];
    float ms = fmaxf(m, m1);
    float a0 = exp2f((m - ms) * LOG2E);
    float a1 = exp2f((m1 - ms) * LOG2E);
    float linv = 1.0f / (lsum * a0 + l1 * a1);
    a0 *= linv; a1 *= linv;
    const float* pb = pbuf + (h01 * 64 + l) * 33;
    float of[32];
#pragma unroll
    for (int r = 0; r < 16; r++) {
      of[r] = oa[0][r] * a0 + pb[r] * a1;
      of[16 + r] = oa[1][r] * a0 + pb[16 + r] * a1;
    }
    // transpose O^T -> O via head-private LDS tile (stride 33), coalesced store
    u32* ot = otileB + h01 * (32 * 33);
#pragma unroll
    for (int dt = 0; dt < 2; dt++)
#pragma unroll
      for (int r = 0; r < 16; r += 2) {
        int d = dt * 32 + (r & 3) + 8 * (r >> 2) + 4 * hi;
        ot[lq * 33 + (d >> 1)] = cvtpk(of[dt * 16 + r], of[dt * 16 + r + 1]);
      }
#pragma unroll
    for (int i2 = 0; i2 < 16; i2++) {
      int wd = i2 * 64 + l;
      int row = wd >> 5, col = wd & 31;
      u32 v = ot[row * 33 + col];
      *(u32*)(Ob + (size_t)(b * 2048 + q0 + row) * 1024 + h * 64 + col * 2) = v;
    }
  }
#undef STAGE
}

extern "C" void kernel_launch(void* const* d_in, const int* in_sizes, int n_in,
                              void* d_out, int out_size, void* d_ws, size_t ws_size,
                              hipStream_t stream) {
  const float* x = (const float*)d_in[0];
  const float* cs = (const float*)d_in[1];
  const float* sn = (const float*)d_in[2];
  const float* w_qkv = (const float*)d_in[3];
  const float* w_out = (const float*)d_in[4];
  float* out = (float*)d_out;
  char* ws = (char*)d_ws;

  u16* Xb   = (u16*)(ws + (size_t)(0u) );          // 8 MB  [4096][1024]
  u16* Wqt  = (u16*)(ws + ((size_t)8u << 20));     // 4 MB  [2048][1024]
  u16* Wot  = (u16*)(ws + ((size_t)12u << 20));    // 2 MB  [1024][1024]
  float* qkv = (float*)(ws + ((size_t)14u << 20)); // 32 MB [4096][2048]
  u16* Qb   = (u16*)(ws + ((size_t)46u << 20));    // 8 MB  [2][16][2048][64]
  u16* Kb   = (u16*)(ws + ((size_t)54u << 20));    // 4 MB  [2][8][2048][64]
  u16* Vt   = (u16*)(ws + ((size_t)58u << 20));    // 4 MB  [2][8][64][2048]
  u16* Ob   = (u16*)(ws + ((size_t)62u << 20));    // 8 MB  [4096][1024]

  k_prep0<<<7168, 256, 0, stream>>>(x, Xb, w_qkv, Wqt, w_out, Wot);
  k_gemm_bt<2048, 1024><<<dim3(32, 16), 256, 0, stream>>>(Xb, Wqt, qkv);
  k_prep1<<<3584, 256, 0, stream>>>(qkv, cs, sn, Qb, Kb, Vt);
  k_flash8<<<1024, 256, 0, stream>>>(Qb, Kb, Vt, Ob);
  k_gemm_bt<1024, 1024><<<dim3(32, 8), 256, 0, stream>>>(Ob, Wot, out);
}

// Round 9
// 104.486 us; speedup vs baseline: 1.6797x; 1.0674x over previous
//
#include <hip/hip_runtime.h>

typedef unsigned short u16;
typedef unsigned int u32;
typedef short bf16x8 __attribute__((ext_vector_type(8)));
typedef float f32x4 __attribute__((ext_vector_type(4)));
typedef float f32x8v __attribute__((ext_vector_type(8)));
typedef float f32x16 __attribute__((ext_vector_type(16)));

#define LOG2E 1.44269504f

__device__ __forceinline__ u16 f2b(float f) {
  union { float f; unsigned u; } v; v.f = f;
  unsigned r = v.u + 0x7FFFu + ((v.u >> 16) & 1u);
  return (u16)(r >> 16);
}

__device__ __forceinline__ u32 pk2(float a, float b) {
  union { float f; u32 u; } x, y; x.f = a; y.f = b;
  return ((x.u + 0x8000u) >> 16) | ((y.u + 0x8000u) & 0xFFFF0000u);
}

__device__ __forceinline__ u32 cvtpk(float a, float b) {
  u32 r;
  asm("v_cvt_pk_bf16_f32 %0, %1, %2" : "=v"(r) : "v"(a), "v"(b));
  return r;
}

__device__ __forceinline__ float max3f(float a, float b, float c) {
  float r;
  asm("v_max3_f32 %0, %1, %2, %3" : "=v"(r) : "v"(a), "v"(b), "v"(c));
  return r;
}

__device__ __forceinline__ void plswap(u32& x, u32& y) {
#if __has_builtin(__builtin_amdgcn_permlane32_swap)
  typedef int v2i __attribute__((ext_vector_type(2)));
  v2i r = __builtin_amdgcn_permlane32_swap((int)x, (int)y, false, false);
  x = (u32)r[0]; y = (u32)r[1];
#else
  u32 sx = (u32)__shfl_xor((int)x, 32, 64);
  u32 sy = (u32)__shfl_xor((int)y, 32, 64);
  bool hi = (threadIdx.x & 63) >= 32;
  u32 nx = hi ? sy : x;
  u32 ny = hi ? y : sx;
  x = nx; y = ny;
#endif
}

// async global->LDS, 16B per lane; LDS dest is wave-uniform base (HW adds lane*16)
__device__ __forceinline__ void gld16(const void* g, void* l) {
  __builtin_amdgcn_global_load_lds((const __attribute__((address_space(1))) void*)g,
                                   (__attribute__((address_space(3))) void*)l, 16, 0, 0);
}

// inverse of LDS fragment swizzle ba(r,o) = (r*64 + o*16) ^ ((r&7)<<4), L = c*16
__device__ __forceinline__ void invswz(int c, int& r, int& o) {
  int rhalf = c >> 3;
  int r2 = (rhalf >> 1) & 1;
  int r0 = ((c >> 2) & 1) ^ r2;
  r = rhalf * 2 + r0;
  int o0 = (c & 1) ^ r0;
  int o1 = ((c >> 1) & 1) ^ (rhalf & 1);
  o = o0 + 2 * o1;
}

// ------------- prep0: cast x (blk<4096) | transpose w_qkv (<6144) | transpose w_out -------------
__global__ __launch_bounds__(256) void k_prep0(const float* __restrict__ x, u16* __restrict__ Xb,
                                               const float* __restrict__ w_qkv, u16* __restrict__ Wqt,
                                               const float* __restrict__ w_out, u16* __restrict__ Wot) {
  __shared__ float tile[32][33];
  int blk = blockIdx.x;
  int tid = threadIdx.x;
  if (blk < 4096) {
    int i = blk * 256 + tid;
    float4 v = ((const float4*)x)[i];
    ushort4 o;
    o.x = f2b(v.x); o.y = f2b(v.y); o.z = f2b(v.z); o.w = f2b(v.w);
    ((ushort4*)Xb)[i] = o;
    return;
  }
  const float* in; u16* out; int R, C, t;
  if (blk < 6144) { t = blk - 4096; in = w_qkv; out = Wqt; R = 1024; C = 2048; }
  else            { t = blk - 6144; in = w_out; out = Wot; R = 1024; C = 1024; }
  int nbx = C >> 5;
  int c0 = (t % nbx) * 32, r0 = (t / nbx) * 32;
  int tx = tid & 31, ty = tid >> 5;
#pragma unroll
  for (int i = 0; i < 32; i += 8)
    tile[ty + i][tx] = in[(size_t)(r0 + ty + i) * C + c0 + tx];
  __syncthreads();
#pragma unroll
  for (int i = 0; i < 32; i += 8)
    out[(size_t)(c0 + ty + i) * R + r0 + tx] = f2b(tile[tx][ty + i]);
}

// ------------- GEMM: BMx128 tile, global_load_lds staging (pre-swizzled source), dbuf, counted vmcnt
// EPI 0: C fp32 store. EPI 1 (qkv): cols<1536 -> in-register RoPE -> Qb/Kb bf16; else Vb bf16.
template<int BM, int Nsz, int Ksz, int EPI>
__global__ __launch_bounds__(256) void k_gemm(const u16* __restrict__ A, const u16* __restrict__ Bt,
                                              float* __restrict__ C, const float* __restrict__ cs,
                                              const float* __restrict__ sn, u16* __restrict__ Qb,
                                              u16* __restrict__ Kb, u16* __restrict__ Vb) {
  constexpr int MT = BM / 32;       // acc m-tiles per wave
  constexpr int CA = BM / 64;       // A staging calls
  __shared__ u16 As[2][BM * 32];
  __shared__ u16 Bs[2][128 * 32];
  const int tid = threadIdx.x;
  const int l = tid & 63, w = tid >> 6;
  const int wm = w >> 1, wn = w & 1;
  const int m0 = blockIdx.x * BM, n0 = blockIdx.y * 128;
  const int rg = l >> 4, cl = l & 15;

  // staging sources: lane's linear LDS slot c -> (row,off) via inverse swizzle
  const u16* aSrc[2];
  const u16* bSrc[2];
#pragma unroll
  for (int i = 0; i < CA; i++) {
    int r, o; invswz(i * 256 + tid, r, o);
    aSrc[i] = A + (size_t)(m0 + r) * Ksz + o * 8;
  }
#pragma unroll
  for (int i = 0; i < 2; i++) {
    int r, o; invswz(i * 256 + tid, r, o);
    bSrc[i] = Bt + (size_t)(n0 + r) * Ksz + o * 8;
  }

  auto stage = [&](int buf) {
#pragma unroll
    for (int i = 0; i < CA; i++) {
      gld16(aSrc[i], (char*)As + buf * (BM * 64) + i * 4096 + w * 1024);
      aSrc[i] += 32;
    }
#pragma unroll
    for (int i = 0; i < 2; i++) {
      gld16(bSrc[i], (char*)Bs + buf * 8192 + i * 4096 + w * 1024);
      bSrc[i] += 32;
    }
  };

  f32x4 acc[MT][4] = {};
  const int NK = Ksz / 32;
  stage(0);
  for (int j = 0; j < NK; j++) {
    const int cur = j & 1;
    if (j + 1 < NK) {
      stage(cur ^ 1);
      if constexpr (CA == 2) asm volatile("s_waitcnt vmcnt(4)" ::: "memory");
      else                   asm volatile("s_waitcnt vmcnt(3)" ::: "memory");
    } else {
      asm volatile("s_waitcnt vmcnt(0)" ::: "memory");
    }
    __builtin_amdgcn_s_barrier();
    asm volatile("" ::: "memory");

    bf16x8 aF[MT], bF[4];
#pragma unroll
    for (int m = 0; m < MT; m++) {
      int row = wm * (BM / 2) + m * 16 + cl;
      unsigned ba = (unsigned)((row * 64 + rg * 16) ^ ((row & 7) << 4));
      aF[m] = *(const bf16x8*)((char*)As[cur] + ba);
    }
#pragma unroll
    for (int n = 0; n < 4; n++) {
      int row = wn * 64 + n * 16 + cl;
      unsigned ba = (unsigned)((row * 64 + rg * 16) ^ ((row & 7) << 4));
      bF[n] = *(const bf16x8*)((char*)Bs[cur] + ba);
    }
    __builtin_amdgcn_s_setprio(1);
#pragma unroll
    for (int m = 0; m < MT; m++)
#pragma unroll
      for (int n = 0; n < 4; n++)
        acc[m][n] = __builtin_amdgcn_mfma_f32_16x16x32_bf16(aF[m], bF[n], acc[m][n], 0, 0, 0);
    __builtin_amdgcn_s_setprio(0);
    asm volatile("" ::: "memory");
    __builtin_amdgcn_s_barrier();
  }

  if constexpr (EPI == 0) {
#pragma unroll
    for (int m = 0; m < MT; m++)
#pragma unroll
      for (int n = 0; n < 4; n++)
#pragma unroll
        for (int r = 0; r < 4; r++)
          C[(size_t)(m0 + wm * (BM / 2) + m * 16 + rg * 4 + r) * Nsz + n0 + wn * 64 + n * 16 + cl] =
              acc[m][n][r];
  } else {
    const int col0 = n0 + wn * 64;   // 64-aligned -> exactly one head
    if (col0 < 1536) {
      const bool isQ = col0 < 1024;
      const float scale = isQ ? 0.125f : 1.0f;
      u16* dst = isQ ? Qb : Kb;
      const int hh = isQ ? (col0 >> 6) : ((col0 - 1024) >> 6);
      const int HN = isQ ? 16 : 8;
#pragma unroll
      for (int m = 0; m < MT; m++)
#pragma unroll
        for (int r = 0; r < 4; r++) {
          int tg = m0 + wm * (BM / 2) + m * 16 + rg * 4 + r;
          int bb = tg >> 11, tt = tg & 2047;
          size_t base = ((size_t)(bb * HN + hh) * 2048 + tt) * 64;
#pragma unroll
          for (int n = 0; n < 4; n++) {
            int d = n * 16 + cl;
            float cv = cs[tt * 64 + d], sv = sn[tt * 64 + d];
            float partner = acc[m][n ^ 2][r];
            float val = acc[m][n][r] * cv + ((n < 2) ? -partner : partner) * sv;
            dst[base + d] = f2b(val * scale);
          }
        }
    } else {
#pragma unroll
      for (int m = 0; m < MT; m++)
#pragma unroll
        for (int r = 0; r < 4; r++) {
          int tg = m0 + wm * (BM / 2) + m * 16 + rg * 4 + r;
#pragma unroll
          for (int n = 0; n < 4; n++)
            Vb[(size_t)tg * 512 + (col0 - 1536) + n * 16 + cl] = f2b(acc[m][n][r]);
        }
    }
  }
}

// ------------- V transpose: Vb bf16 [4096][512] -> Vt[b*8+kh][64][2048] bf16 -------------
__global__ __launch_bounds__(256) void k_vtrans(const u16* __restrict__ Vb, u16* __restrict__ Vt) {
  __shared__ u16 tile[64][65];
  int blk = blockIdx.x;
  int t0 = (blk & 31) * 64;
  int bh = blk >> 5;  // b*8+kh
  int tx = threadIdx.x & 63, ty = threadIdx.x >> 6;
  const u16* src = Vb + ((size_t)((bh >> 3) * 2048 + t0)) * 512 + (bh & 7) * 64;
#pragma unroll
  for (int i = 0; i < 64; i += 4)
    tile[ty + i][tx] = src[(size_t)(ty + i) * 512 + tx];
  __syncthreads();
  u16* dst = Vt + (size_t)bh * 64 * 2048 + t0;
#pragma unroll
  for (int i = 0; i < 64; i += 4)
    dst[(size_t)(ty + i) * 2048 + tx] = tile[tx][ty + i];
}

// ---- causal flash attention v9: flash8 + conflict-free swizzles (row^(row>>3) family) ----
__global__ __launch_bounds__(256, 4) void k_flash9(const u16* __restrict__ Qb, const u16* __restrict__ Kb,
                                                   const u16* __restrict__ Vt, u16* __restrict__ Ob) {
  __shared__ u16 smem[16384];  // 32KB: 2 streams x [K dbuf 2x4KB | V dbuf 2x4KB]
  const int tid = threadIdx.x;
  const int l = tid & 63, w = tid >> 6;
  const int sid = w >> 1;        // kv stream 0..1
  const int h01 = w & 1;         // head within kh
  const int bid = blockIdx.x;
  const int bkh = bid & 15, qt = 63 - (bid >> 4);  // kh fastest (XCD L2), qt descending (LPT)
  const int b = bkh >> 3, kh = bkh & 7;
  const int h = kh * 2 + h01;
  const int q0 = qt * 32;
  const int lq = l & 31, hi = l >> 5;
  const int q = q0 + lq;

  const int cnt = (qt + 2 - sid) >> 1;   // tiles for this stream (t = sid + 2i)
  const int CNTMAX = (qt + 2) >> 1;

  const u16* Kg = Kb + (size_t)(b * 8 + kh) * 2048 * 64;
  const u16* Vg = Vt + (size_t)(b * 8 + kh) * 64 * 2048;
  const u16* Qp = Qb + ((size_t)(b * 16 + h) * 2048 + q) * 64 + hi * 8;

  // ---- hoisted staging pointers, swz(row) = (row ^ (row>>3)) (K: &7 / V: &3 on (d>>1)) ----
  const int krow = h01 * 16 + (l >> 3);
  const int swk1 = (krow ^ (krow >> 3)) & 7;
  const int swk2 = ((krow + 8) ^ ((krow + 8) >> 3)) & 7;
  const u16* kS1 = Kg + (size_t)(sid * 32 + krow) * 64 + (((l & 7) ^ swk1) << 3);
  const u16* kS2 = Kg + (size_t)(sid * 32 + krow + 8) * 64 + (((l & 7) ^ swk2) << 3);
  const int vd = h01 * 32 + (l >> 2);
  const int swv1 = ((vd >> 1) ^ (vd >> 3)) & 3;
  const int swv2 = (((vd + 16) >> 1) ^ ((vd + 16) >> 3)) & 3;
  const u16* vS0 = Vg + (size_t)vd * 2048 + sid * 32 + (((l & 3) ^ swv1) << 3);
  const u16* vS1 = Vg + (size_t)(vd + 16) * 2048 + sid * 32 + (((l & 3) ^ swv2) << 3);
  char* smB = (char*)smem;
  const int kDst = sid * 16384 + h01 * 2048;
  const int vDst = sid * 16384 + 8192 + h01 * 2048;

#define STAGE(buf)                                         \
  {                                                        \
    gld16(kS1, smB + kDst + (buf) * 4096);                 \
    gld16(kS2, smB + kDst + (buf) * 4096 + 1024);          \
    gld16(vS0, smB + vDst + (buf) * 4096);                 \
    gld16(vS1, smB + vDst + (buf) * 4096 + 1024);          \
    kS1 += 4096; kS2 += 4096; vS0 += 64; vS1 += 64;        \
  }

  if (cnt > 0) STAGE(0);

  bf16x8 qf[4];
#pragma unroll
  for (int ks = 0; ks < 4; ks++) qf[ks] = *(const bf16x8*)(Qp + ks * 16);

  union { u32 uu[4]; bf16x8 v; } ones;
#pragma unroll
  for (int j = 0; j < 4; j++) ones.uu[j] = 0x3F803F80u;

  f32x16 oa[2] = {};
  f32x16 lacc = {};
  float m = -3e38f;
  const int swzkr = (lq ^ (lq >> 3)) & 7;
  const int swzvr = ((lq >> 1) ^ (lq >> 3)) & 3;

  for (int i = 0; i < CNTMAX; i++) {
    const int cur = i & 1;
    if (i + 1 < cnt) {
      STAGE(cur ^ 1);
      asm volatile("s_waitcnt vmcnt(4)" ::: "memory");
    } else {
      asm volatile("s_waitcnt vmcnt(0)" ::: "memory");
    }
    __builtin_amdgcn_s_barrier();
    asm volatile("" ::: "memory");

    if (i < cnt) {
      const int t = sid + 2 * i;
      const char* KL = smB + sid * 16384 + cur * 4096;
      const char* VL = smB + sid * 16384 + 8192 + cur * 4096;

      bf16x8 kf[4];
#pragma unroll
      for (int ks = 0; ks < 4; ks++)
        kf[ks] = *(const bf16x8*)(KL + lq * 128 + ((((ks << 1) | hi) ^ swzkr) << 4));
      f32x16 s0 = {};
      __builtin_amdgcn_s_setprio(1);
#pragma unroll
      for (int ks = 0; ks < 4; ks++)
        s0 = __builtin_amdgcn_mfma_f32_32x32x16_bf16(kf[ks], qf[ks], s0, 0, 0, 0);
      __builtin_amdgcn_s_setprio(0);

      if (t == qt) {
#pragma unroll
        for (int r = 0; r < 16; r++) {
          int kvr = (t << 5) + (r & 3) + 8 * (r >> 2) + 4 * hi;
          if (kvr > q) s0[r] = -3e38f;
        }
      }

      float a5[5];
#pragma unroll
      for (int j = 0; j < 5; j++) a5[j] = max3f(s0[3 * j], s0[3 * j + 1], s0[3 * j + 2]);
      float mx16 = fmaxf(max3f(a5[0], a5[1], a5[2]), max3f(a5[3], a5[4], s0[15]));
      bool keep = __all(mx16 - m <= 8.f);
      if (!keep) {
        float mx = fmaxf(mx16, __shfl_xor(mx16, 32, 64));
        float mnew = fmaxf(m, mx);
        float alpha = exp2f((m - mnew) * LOG2E);
        m = mnew;
        lacc[0] *= alpha;
#pragma unroll
        for (int r = 0; r < 16; r++) { oa[0][r] *= alpha; oa[1][r] *= alpha; }
      }
      float mb = m * LOG2E;
#pragma unroll
      for (int r = 0; r < 16; r++) s0[r] = exp2f(fmaf(s0[r], LOG2E, -mb));

      u32 aw[8];
#pragma unroll
      for (int j = 0; j < 8; j++) aw[j] = cvtpk(s0[2 * j], s0[2 * j + 1]);
      plswap(aw[0], aw[2]); plswap(aw[1], aw[3]);
      plswap(aw[4], aw[6]); plswap(aw[5], aw[7]);
      union { u32 uu[4]; bf16x8 v; } p0, p1;
#pragma unroll
      for (int j = 0; j < 4; j++) { p0.uu[j] = aw[j]; p1.uu[j] = aw[4 + j]; }

      bf16x8 vf[2][2];
#pragma unroll
      for (int dt = 0; dt < 2; dt++)
#pragma unroll
        for (int p = 0; p < 2; p++)
          vf[dt][p] = *(const bf16x8*)(VL + (dt * 32 + lq) * 64 + ((((p << 1) | hi) ^ swzvr) << 4));

      __builtin_amdgcn_s_setprio(1);
#pragma unroll
      for (int dt = 0; dt < 2; dt++) {
        oa[dt] = __builtin_amdgcn_mfma_f32_32x32x16_bf16(vf[dt][0], p0.v, oa[dt], 0, 0, 0);
        oa[dt] = __builtin_amdgcn_mfma_f32_32x32x16_bf16(vf[dt][1], p1.v, oa[dt], 0, 0, 0);
      }
      lacc = __builtin_amdgcn_mfma_f32_32x32x16_bf16(ones.v, p0.v, lacc, 0, 0, 0);
      lacc = __builtin_amdgcn_mfma_f32_32x32x16_bf16(ones.v, p1.v, lacc, 0, 0, 0);
      __builtin_amdgcn_s_setprio(0);
    }

    asm volatile("" ::: "memory");
    __builtin_amdgcn_s_barrier();
  }

  float lsum = lacc[0];

  // ---- 2-way merge per head (overlay staging LDS) ----
  __syncthreads();
  float* pbuf = (float*)smem;                       // [2][64][33] f32
  float* mlb = (float*)((char*)smem + 16896);       // [2][128] f32
  u32* otileB = (u32*)((char*)smem + 17920);        // [2][32*33] u32
  if (sid == 1) {
    float* pb = pbuf + (h01 * 64 + l) * 33;
#pragma unroll
    for (int r = 0; r < 16; r++) { pb[r] = oa[0][r]; pb[16 + r] = oa[1][r]; }
    mlb[h01 * 128 + l] = m;
    mlb[h01 * 128 + 64 + l] = lsum;
  }
  __syncthreads();
  if (sid == 0) {
    float m1 = mlb[h01 * 128 + l], l1 = mlb[h01 * 128 + 64 + l];
    float ms = fmaxf(m, m1);
    float a0 = exp2f((m - ms) * LOG2E);
    float a1 = exp2f((m1 - ms) * LOG2E);
    float linv = 1.0f / (lsum * a0 + l1 * a1);
    a0 *= linv; a1 *= linv;
    const float* pb = pbuf + (h01 * 64 + l) * 33;
    float of[32];
#pragma unroll
    for (int r = 0; r < 16; r++) {
      of[r] = oa[0][r] * a0 + pb[r] * a1;
      of[16 + r] = oa[1][r] * a0 + pb[16 + r] * a1;
    }
    u32* ot = otileB + h01 * (32 * 33);
#pragma unroll
    for (int dt = 0; dt < 2; dt++)
#pragma unroll
      for (int r = 0; r < 16; r += 2) {
        int d = dt * 32 + (r & 3) + 8 * (r >> 2) + 4 * hi;
        ot[lq * 33 + (d >> 1)] = cvtpk(of[dt * 16 + r], of[dt * 16 + r + 1]);
      }
#pragma unroll
    for (int i2 = 0; i2 < 16; i2++) {
      int wd = i2 * 64 + l;
      int row = wd >> 5, col = wd & 31;
      u32 v = ot[row * 33 + col];
      *(u32*)(Ob + (size_t)(b * 2048 + q0 + row) * 1024 + h * 64 + col * 2) = v;
    }
  }
#undef STAGE
}

extern "C" void kernel_launch(void* const* d_in, const int* in_sizes, int n_in,
                              void* d_out, int out_size, void* d_ws, size_t ws_size,
                              hipStream_t stream) {
  const float* x = (const float*)d_in[0];
  const float* cs = (const float*)d_in[1];
  const float* sn = (const float*)d_in[2];
  const float* w_qkv = (const float*)d_in[3];
  const float* w_out = (const float*)d_in[4];
  float* out = (float*)d_out;
  char* ws = (char*)d_ws;

  u16* Xb  = (u16*)(ws);                       // 8 MB  [4096][1024]
  u16* Wqt = (u16*)(ws + ((size_t)8u << 20));  // 4 MB  [2048][1024]
  u16* Wot = (u16*)(ws + ((size_t)12u << 20)); // 2 MB  [1024][1024]
  u16* Vb  = (u16*)(ws + ((size_t)14u << 20)); // 4 MB  [4096][512] bf16
  u16* Qb  = (u16*)(ws + ((size_t)18u << 20)); // 8 MB  [2][16][2048][64]
  u16* Kb  = (u16*)(ws + ((size_t)26u << 20)); // 4 MB  [2][8][2048][64]
  u16* Vt  = (u16*)(ws + ((size_t)30u << 20)); // 4 MB  [2][8][64][2048]
  u16* Ob  = (u16*)(ws + ((size_t)34u << 20)); // 8 MB  [4096][1024]

  k_prep0<<<7168, 256, 0, stream>>>(x, Xb, w_qkv, Wqt, w_out, Wot);
  k_gemm<128, 2048, 1024, 1><<<dim3(32, 16), 256, 0, stream>>>(Xb, Wqt, nullptr, cs, sn, Qb, Kb, Vb);
  k_vtrans<<<512, 256, 0, stream>>>(Vb, Vt);
  k_flash9<<<1024, 256, 0, stream>>>(Qb, Kb, Vt, Ob);
  k_gemm<64, 1024, 1024, 0><<<dim3(64, 8), 256, 0, stream>>>(Ob, Wot, out, nullptr, nullptr, nullptr, nullptr, nullptr);
}

// Round 10
// 102.346 us; speedup vs baseline: 1.7148x; 1.0209x over previous
//
#include <hip/hip_runtime.h>

typedef unsigned short u16;
typedef unsigned int u32;
typedef short bf16x8 __attribute__((ext_vector_type(8)));
typedef float f32x4 __attribute__((ext_vector_type(4)));
typedef float f32x8v __attribute__((ext_vector_type(8)));
typedef float f32x16 __attribute__((ext_vector_type(16)));

#define LOG2E 1.44269504f

__device__ __forceinline__ u16 f2b(float f) {
  union { float f; unsigned u; } v; v.f = f;
  unsigned r = v.u + 0x7FFFu + ((v.u >> 16) & 1u);
  return (u16)(r >> 16);
}

__device__ __forceinline__ u32 pk2(float a, float b) {
  union { float f; u32 u; } x, y; x.f = a; y.f = b;
  return ((x.u + 0x8000u) >> 16) | ((y.u + 0x8000u) & 0xFFFF0000u);
}

__device__ __forceinline__ u32 cvtpk(float a, float b) {
  u32 r;
  asm("v_cvt_pk_bf16_f32 %0, %1, %2" : "=v"(r) : "v"(a), "v"(b));
  return r;
}

__device__ __forceinline__ float max3f(float a, float b, float c) {
  float r;
  asm("v_max3_f32 %0, %1, %2, %3" : "=v"(r) : "v"(a), "v"(b), "v"(c));
  return r;
}

__device__ __forceinline__ void plswap(u32& x, u32& y) {
#if __has_builtin(__builtin_amdgcn_permlane32_swap)
  typedef int v2i __attribute__((ext_vector_type(2)));
  v2i r = __builtin_amdgcn_permlane32_swap((int)x, (int)y, false, false);
  x = (u32)r[0]; y = (u32)r[1];
#else
  u32 sx = (u32)__shfl_xor((int)x, 32, 64);
  u32 sy = (u32)__shfl_xor((int)y, 32, 64);
  bool hi = (threadIdx.x & 63) >= 32;
  u32 nx = hi ? sy : x;
  u32 ny = hi ? y : sx;
  x = nx; y = ny;
#endif
}

// async global->LDS, 16B per lane; LDS dest is wave-uniform base (HW adds lane*16)
__device__ __forceinline__ void gld16(const void* g, void* l) {
  __builtin_amdgcn_global_load_lds((const __attribute__((address_space(1))) void*)g,
                                   (__attribute__((address_space(3))) void*)l, 16, 0, 0);
}

// inverse of LDS fragment swizzle ba(r,o) = (r*64 + o*16) ^ ((r&7)<<4), L = c*16
__device__ __forceinline__ void invswz(int c, int& r, int& o) {
  int rhalf = c >> 3;
  int r2 = (rhalf >> 1) & 1;
  int r0 = ((c >> 2) & 1) ^ r2;
  r = rhalf * 2 + r0;
  int o0 = (c & 1) ^ r0;
  int o1 = ((c >> 1) & 1) ^ (rhalf & 1);
  o = o0 + 2 * o1;
}

// ------------- prep0: cast x (blk<4096) | transpose w_qkv (<6144) | transpose w_out -------------
__global__ __launch_bounds__(256) void k_prep0(const float* __restrict__ x, u16* __restrict__ Xb,
                                               const float* __restrict__ w_qkv, u16* __restrict__ Wqt,
                                               const float* __restrict__ w_out, u16* __restrict__ Wot) {
  __shared__ float tile[32][33];
  int blk = blockIdx.x;
  int tid = threadIdx.x;
  if (blk < 4096) {
    int i = blk * 256 + tid;
    float4 v = ((const float4*)x)[i];
    ushort4 o;
    o.x = f2b(v.x); o.y = f2b(v.y); o.z = f2b(v.z); o.w = f2b(v.w);
    ((ushort4*)Xb)[i] = o;
    return;
  }
  const float* in; u16* out; int R, C, t;
  if (blk < 6144) { t = blk - 4096; in = w_qkv; out = Wqt; R = 1024; C = 2048; }
  else            { t = blk - 6144; in = w_out; out = Wot; R = 1024; C = 1024; }
  int nbx = C >> 5;
  int c0 = (t % nbx) * 32, r0 = (t / nbx) * 32;
  int tx = tid & 31, ty = tid >> 5;
#pragma unroll
  for (int i = 0; i < 32; i += 8)
    tile[ty + i][tx] = in[(size_t)(r0 + ty + i) * C + c0 + tx];
  __syncthreads();
#pragma unroll
  for (int i = 0; i < 32; i += 8)
    out[(size_t)(c0 + ty + i) * R + r0 + tx] = f2b(tile[tx][ty + i]);
}

// ------------- GEMM: BMx128 tile, global_load_lds staging (pre-swizzled source), dbuf, counted vmcnt
// EPI 0: C fp32 store. EPI 1 (qkv): cols<1536 -> in-register RoPE -> Qb/Kb bf16; else Vb bf16.
template<int BM, int Nsz, int Ksz, int EPI>
__global__ __launch_bounds__(256) void k_gemm(const u16* __restrict__ A, const u16* __restrict__ Bt,
                                              float* __restrict__ C, const float* __restrict__ cs,
                                              const float* __restrict__ sn, u16* __restrict__ Qb,
                                              u16* __restrict__ Kb, u16* __restrict__ Vb) {
  constexpr int MT = BM / 32;       // acc m-tiles per wave
  constexpr int CA = BM / 64;       // A staging calls
  __shared__ u16 As[2][BM * 32];
  __shared__ u16 Bs[2][128 * 32];
  const int tid = threadIdx.x;
  const int l = tid & 63, w = tid >> 6;
  const int wm = w >> 1, wn = w & 1;
  const int m0 = blockIdx.x * BM, n0 = blockIdx.y * 128;
  const int rg = l >> 4, cl = l & 15;

  // staging sources: lane's linear LDS slot c -> (row,off) via inverse swizzle
  const u16* aSrc[2];
  const u16* bSrc[2];
#pragma unroll
  for (int i = 0; i < CA; i++) {
    int r, o; invswz(i * 256 + tid, r, o);
    aSrc[i] = A + (size_t)(m0 + r) * Ksz + o * 8;
  }
#pragma unroll
  for (int i = 0; i < 2; i++) {
    int r, o; invswz(i * 256 + tid, r, o);
    bSrc[i] = Bt + (size_t)(n0 + r) * Ksz + o * 8;
  }

  auto stage = [&](int buf) {
#pragma unroll
    for (int i = 0; i < CA; i++) {
      gld16(aSrc[i], (char*)As + buf * (BM * 64) + i * 4096 + w * 1024);
      aSrc[i] += 32;
    }
#pragma unroll
    for (int i = 0; i < 2; i++) {
      gld16(bSrc[i], (char*)Bs + buf * 8192 + i * 4096 + w * 1024);
      bSrc[i] += 32;
    }
  };

  f32x4 acc[MT][4] = {};
  const int NK = Ksz / 32;
  stage(0);
  for (int j = 0; j < NK; j++) {
    const int cur = j & 1;
    if (j + 1 < NK) {
      stage(cur ^ 1);
      if constexpr (CA == 2) asm volatile("s_waitcnt vmcnt(4)" ::: "memory");
      else                   asm volatile("s_waitcnt vmcnt(3)" ::: "memory");
    } else {
      asm volatile("s_waitcnt vmcnt(0)" ::: "memory");
    }
    __builtin_amdgcn_s_barrier();
    asm volatile("" ::: "memory");

    bf16x8 aF[MT], bF[4];
#pragma unroll
    for (int m = 0; m < MT; m++) {
      int row = wm * (BM / 2) + m * 16 + cl;
      unsigned ba = (unsigned)((row * 64 + rg * 16) ^ ((row & 7) << 4));
      aF[m] = *(const bf16x8*)((char*)As[cur] + ba);
    }
#pragma unroll
    for (int n = 0; n < 4; n++) {
      int row = wn * 64 + n * 16 + cl;
      unsigned ba = (unsigned)((row * 64 + rg * 16) ^ ((row & 7) << 4));
      bF[n] = *(const bf16x8*)((char*)Bs[cur] + ba);
    }
    __builtin_amdgcn_s_setprio(1);
#pragma unroll
    for (int m = 0; m < MT; m++)
#pragma unroll
      for (int n = 0; n < 4; n++)
        acc[m][n] = __builtin_amdgcn_mfma_f32_16x16x32_bf16(aF[m], bF[n], acc[m][n], 0, 0, 0);
    __builtin_amdgcn_s_setprio(0);
    asm volatile("" ::: "memory");
    __builtin_amdgcn_s_barrier();
  }

  if constexpr (EPI == 0) {
#pragma unroll
    for (int m = 0; m < MT; m++)
#pragma unroll
      for (int n = 0; n < 4; n++)
#pragma unroll
        for (int r = 0; r < 4; r++)
          C[(size_t)(m0 + wm * (BM / 2) + m * 16 + rg * 4 + r) * Nsz + n0 + wn * 64 + n * 16 + cl] =
              acc[m][n][r];
  } else {
    const int col0 = n0 + wn * 64;   // 64-aligned -> exactly one head
    if (col0 < 1536) {
      const bool isQ = col0 < 1024;
      const float scale = isQ ? 0.125f : 1.0f;
      u16* dst = isQ ? Qb : Kb;
      const int hh = isQ ? (col0 >> 6) : ((col0 - 1024) >> 6);
      const int HN = isQ ? 16 : 8;
#pragma unroll
      for (int m = 0; m < MT; m++)
#pragma unroll
        for (int r = 0; r < 4; r++) {
          int tg = m0 + wm * (BM / 2) + m * 16 + rg * 4 + r;
          int bb = tg >> 11, tt = tg & 2047;
          size_t base = ((size_t)(bb * HN + hh) * 2048 + tt) * 64;
#pragma unroll
          for (int n = 0; n < 4; n++) {
            int d = n * 16 + cl;
            float cv = cs[tt * 64 + d], sv = sn[tt * 64 + d];
            float partner = acc[m][n ^ 2][r];
            float val = acc[m][n][r] * cv + ((n < 2) ? -partner : partner) * sv;
            dst[base + d] = f2b(val * scale);
          }
        }
    } else {
#pragma unroll
      for (int m = 0; m < MT; m++)
#pragma unroll
        for (int r = 0; r < 4; r++) {
          int tg = m0 + wm * (BM / 2) + m * 16 + rg * 4 + r;
#pragma unroll
          for (int n = 0; n < 4; n++)
            Vb[(size_t)tg * 512 + (col0 - 1536) + n * 16 + cl] = f2b(acc[m][n][r]);
        }
    }
  }
}

// ------------- V transpose: Vb bf16 [4096][512] -> Vt[b*8+kh][64][2048] bf16 -------------
__global__ __launch_bounds__(256) void k_vtrans(const u16* __restrict__ Vb, u16* __restrict__ Vt) {
  __shared__ u16 tile[64][65];
  int blk = blockIdx.x;
  int t0 = (blk & 31) * 64;
  int bh = blk >> 5;  // b*8+kh
  int tx = threadIdx.x & 63, ty = threadIdx.x >> 6;
  const u16* src = Vb + ((size_t)((bh >> 3) * 2048 + t0)) * 512 + (bh & 7) * 64;
#pragma unroll
  for (int i = 0; i < 64; i += 4)
    tile[ty + i][tx] = src[(size_t)(ty + i) * 512 + tx];
  __syncthreads();
  u16* dst = Vt + (size_t)bh * 64 * 2048 + t0;
#pragma unroll
  for (int i = 0; i < 64; i += 4)
    dst[(size_t)(ty + i) * 2048 + tx] = tile[tx][ty + i];
}

// ---- causal flash attention v10: flash9 + per-CU work equalization ----
// qt from j=bid>>4 via anti-correlated quadrants {63-j, j-16, 79-j, j-32}: every CU's 4
// resident blocks sum to 126 qt-total = 67 tile-steps (was 52..82). kh=bid&7 XCD pinning kept.
__global__ __launch_bounds__(256, 4) void k_flash10(const u16* __restrict__ Qb, const u16* __restrict__ Kb,
                                                    const u16* __restrict__ Vt, u16* __restrict__ Ob) {
  __shared__ u16 smem[16384];  // 32KB: 2 streams x [K dbuf 2x4KB | V dbuf 2x4KB]
  const int tid = threadIdx.x;
  const int l = tid & 63, w = tid >> 6;
  const int sid = w >> 1;        // kv stream 0..1
  const int h01 = w & 1;         // head within kh
  const int bid = blockIdx.x;
  const int bkh = bid & 15;
  const int j = bid >> 4, quad = j >> 4, jj = j & 15;
  const int qt = (quad == 0) ? 63 - jj : (quad == 1) ? jj : (quad == 2) ? 47 - jj : 16 + jj;
  const int b = bkh >> 3, kh = bkh & 7;
  const int h = kh * 2 + h01;
  const int q0 = qt * 32;
  const int lq = l & 31, hi = l >> 5;
  const int q = q0 + lq;

  const int cnt = (qt + 2 - sid) >> 1;   // tiles for this stream (t = sid + 2i)
  const int CNTMAX = (qt + 2) >> 1;

  const u16* Kg = Kb + (size_t)(b * 8 + kh) * 2048 * 64;
  const u16* Vg = Vt + (size_t)(b * 8 + kh) * 64 * 2048;
  const u16* Qp = Qb + ((size_t)(b * 16 + h) * 2048 + q) * 64 + hi * 8;

  // ---- hoisted staging pointers, swz(row) = (row ^ (row>>3)) (K: &7 / V: &3 on (d>>1)) ----
  const int krow = h01 * 16 + (l >> 3);
  const int swk1 = (krow ^ (krow >> 3)) & 7;
  const int swk2 = ((krow + 8) ^ ((krow + 8) >> 3)) & 7;
  const u16* kS1 = Kg + (size_t)(sid * 32 + krow) * 64 + (((l & 7) ^ swk1) << 3);
  const u16* kS2 = Kg + (size_t)(sid * 32 + krow + 8) * 64 + (((l & 7) ^ swk2) << 3);
  const int vd = h01 * 32 + (l >> 2);
  const int swv1 = ((vd >> 1) ^ (vd >> 3)) & 3;
  const int swv2 = (((vd + 16) >> 1) ^ ((vd + 16) >> 3)) & 3;
  const u16* vS0 = Vg + (size_t)vd * 2048 + sid * 32 + (((l & 3) ^ swv1) << 3);
  const u16* vS1 = Vg + (size_t)(vd + 16) * 2048 + sid * 32 + (((l & 3) ^ swv2) << 3);
  char* smB = (char*)smem;
  const int kDst = sid * 16384 + h01 * 2048;
  const int vDst = sid * 16384 + 8192 + h01 * 2048;

#define STAGE(buf)                                         \
  {                                                        \
    gld16(kS1, smB + kDst + (buf) * 4096);                 \
    gld16(kS2, smB + kDst + (buf) * 4096 + 1024);          \
    gld16(vS0, smB + vDst + (buf) * 4096);                 \
    gld16(vS1, smB + vDst + (buf) * 4096 + 1024);          \
    kS1 += 4096; kS2 += 4096; vS0 += 64; vS1 += 64;        \
  }

  if (cnt > 0) STAGE(0);

  bf16x8 qf[4];
#pragma unroll
  for (int ks = 0; ks < 4; ks++) qf[ks] = *(const bf16x8*)(Qp + ks * 16);

  union { u32 uu[4]; bf16x8 v; } ones;
#pragma unroll
  for (int jo = 0; jo < 4; jo++) ones.uu[jo] = 0x3F803F80u;

  f32x16 oa[2] = {};
  f32x16 lacc = {};
  float m = -3e38f;
  const int swzkr = (lq ^ (lq >> 3)) & 7;
  const int swzvr = ((lq >> 1) ^ (lq >> 3)) & 3;

  for (int i = 0; i < CNTMAX; i++) {
    const int cur = i & 1;
    if (i + 1 < cnt) {
      STAGE(cur ^ 1);
      asm volatile("s_waitcnt vmcnt(4)" ::: "memory");
    } else {
      asm volatile("s_waitcnt vmcnt(0)" ::: "memory");
    }
    __builtin_amdgcn_s_barrier();
    asm volatile("" ::: "memory");

    if (i < cnt) {
      const int t = sid + 2 * i;
      const char* KL = smB + sid * 16384 + cur * 4096;
      const char* VL = smB + sid * 16384 + 8192 + cur * 4096;

      bf16x8 kf[4];
#pragma unroll
      for (int ks = 0; ks < 4; ks++)
        kf[ks] = *(const bf16x8*)(KL + lq * 128 + ((((ks << 1) | hi) ^ swzkr) << 4));
      f32x16 s0 = {};
      __builtin_amdgcn_s_setprio(1);
#pragma unroll
      for (int ks = 0; ks < 4; ks++)
        s0 = __builtin_amdgcn_mfma_f32_32x32x16_bf16(kf[ks], qf[ks], s0, 0, 0, 0);
      __builtin_amdgcn_s_setprio(0);

      if (t == qt) {
#pragma unroll
        for (int r = 0; r < 16; r++) {
          int kvr = (t << 5) + (r & 3) + 8 * (r >> 2) + 4 * hi;
          if (kvr > q) s0[r] = -3e38f;
        }
      }

      float a5[5];
#pragma unroll
      for (int jo = 0; jo < 5; jo++) a5[jo] = max3f(s0[3 * jo], s0[3 * jo + 1], s0[3 * jo + 2]);
      float mx16 = fmaxf(max3f(a5[0], a5[1], a5[2]), max3f(a5[3], a5[4], s0[15]));
      bool keep = __all(mx16 - m <= 8.f);
      if (!keep) {
        float mx = fmaxf(mx16, __shfl_xor(mx16, 32, 64));
        float mnew = fmaxf(m, mx);
        float alpha = exp2f((m - mnew) * LOG2E);
        m = mnew;
        lacc[0] *= alpha;
#pragma unroll
        for (int r = 0; r < 16; r++) { oa[0][r] *= alpha; oa[1][r] *= alpha; }
      }
      float mb = m * LOG2E;
#pragma unroll
      for (int r = 0; r < 16; r++) s0[r] = exp2f(fmaf(s0[r], LOG2E, -mb));

      u32 aw[8];
#pragma unroll
      for (int jo = 0; jo < 8; jo++) aw[jo] = cvtpk(s0[2 * jo], s0[2 * jo + 1]);
      plswap(aw[0], aw[2]); plswap(aw[1], aw[3]);
      plswap(aw[4], aw[6]); plswap(aw[5], aw[7]);
      union { u32 uu[4]; bf16x8 v; } p0, p1;
#pragma unroll
      for (int jo = 0; jo < 4; jo++) { p0.uu[jo] = aw[jo]; p1.uu[jo] = aw[4 + jo]; }

      bf16x8 vf[2][2];
#pragma unroll
      for (int dt = 0; dt < 2; dt++)
#pragma unroll
        for (int p = 0; p < 2; p++)
          vf[dt][p] = *(const bf16x8*)(VL + (dt * 32 + lq) * 64 + ((((p << 1) | hi) ^ swzvr) << 4));

      __builtin_amdgcn_s_setprio(1);
#pragma unroll
      for (int dt = 0; dt < 2; dt++) {
        oa[dt] = __builtin_amdgcn_mfma_f32_32x32x16_bf16(vf[dt][0], p0.v, oa[dt], 0, 0, 0);
        oa[dt] = __builtin_amdgcn_mfma_f32_32x32x16_bf16(vf[dt][1], p1.v, oa[dt], 0, 0, 0);
      }
      lacc = __builtin_amdgcn_mfma_f32_32x32x16_bf16(ones.v, p0.v, lacc, 0, 0, 0);
      lacc = __builtin_amdgcn_mfma_f32_32x32x16_bf16(ones.v, p1.v, lacc, 0, 0, 0);
      __builtin_amdgcn_s_setprio(0);
    }

    asm volatile("" ::: "memory");
    __builtin_amdgcn_s_barrier();
  }

  float lsum = lacc[0];

  // ---- 2-way merge per head (overlay staging LDS) ----
  __syncthreads();
  float* pbuf = (float*)smem;                       // [2][64][33] f32
  float* mlb = (float*)((char*)smem + 16896);       // [2][128] f32
  u32* otileB = (u32*)((char*)smem + 17920);        // [2][32*33] u32
  if (sid == 1) {
    float* pb = pbuf + (h01 * 64 + l) * 33;
#pragma unroll
    for (int r = 0; r < 16; r++) { pb[r] = oa[0][r]; pb[16 + r] = oa[1][r]; }
    mlb[h01 * 128 + l] = m;
    mlb[h01 * 128 + 64 + l] = lsum;
  }
  __syncthreads();
  if (sid == 0) {
    float m1 = mlb[h01 * 128 + l], l1 = mlb[h01 * 128 + 64 + l];
    float ms = fmaxf(m, m1);
    float a0 = exp2f((m - ms) * LOG2E);
    float a1 = exp2f((m1 - ms) * LOG2E);
    float linv = 1.0f / (lsum * a0 + l1 * a1);
    a0 *= linv; a1 *= linv;
    const float* pb = pbuf + (h01 * 64 + l) * 33;
    float of[32];
#pragma unroll
    for (int r = 0; r < 16; r++) {
      of[r] = oa[0][r] * a0 + pb[r] * a1;
      of[16 + r] = oa[1][r] * a0 + pb[16 + r] * a1;
    }
    u32* ot = otileB + h01 * (32 * 33);
#pragma unroll
    for (int dt = 0; dt < 2; dt++)
#pragma unroll
      for (int r = 0; r < 16; r += 2) {
        int d = dt * 32 + (r & 3) + 8 * (r >> 2) + 4 * hi;
        ot[lq * 33 + (d >> 1)] = cvtpk(of[dt * 16 + r], of[dt * 16 + r + 1]);
      }
#pragma unroll
    for (int i2 = 0; i2 < 16; i2++) {
      int wd = i2 * 64 + l;
      int row = wd >> 5, col = wd & 31;
      u32 v = ot[row * 33 + col];
      *(u32*)(Ob + (size_t)(b * 2048 + q0 + row) * 1024 + h * 64 + col * 2) = v;
    }
  }
#undef STAGE
}

extern "C" void kernel_launch(void* const* d_in, const int* in_sizes, int n_in,
                              void* d_out, int out_size, void* d_ws, size_t ws_size,
                              hipStream_t stream) {
  const float* x = (const float*)d_in[0];
  const float* cs = (const float*)d_in[1];
  const float* sn = (const float*)d_in[2];
  const float* w_qkv = (const float*)d_in[3];
  const float* w_out = (const float*)d_in[4];
  float* out = (float*)d_out;
  char* ws = (char*)d_ws;

  u16* Xb  = (u16*)(ws);                       // 8 MB  [4096][1024]
  u16* Wqt = (u16*)(ws + ((size_t)8u << 20));  // 4 MB  [2048][1024]
  u16* Wot = (u16*)(ws + ((size_t)12u << 20)); // 2 MB  [1024][1024]
  u16* Vb  = (u16*)(ws + ((size_t)14u << 20)); // 4 MB  [4096][512] bf16
  u16* Qb  = (u16*)(ws + ((size_t)18u << 20)); // 8 MB  [2][16][2048][64]
  u16* Kb  = (u16*)(ws + ((size_t)26u << 20)); // 4 MB  [2][8][2048][64]
  u16* Vt  = (u16*)(ws + ((size_t)30u << 20)); // 4 MB  [2][8][64][2048]
  u16* Ob  = (u16*)(ws + ((size_t)34u << 20)); // 8 MB  [4096][1024]

  k_prep0<<<7168, 256, 0, stream>>>(x, Xb, w_qkv, Wqt, w_out, Wot);
  k_gemm<128, 2048, 1024, 1><<<dim3(32, 16), 256, 0, stream>>>(Xb, Wqt, nullptr, cs, sn, Qb, Kb, Vb);
  k_vtrans<<<512, 256, 0, stream>>>(Vb, Vt);
  k_flash10<<<1024, 256, 0, stream>>>(Qb, Kb, Vt, Ob);
  k_gemm<64, 1024, 1024, 0><<<dim3(64, 8), 256, 0, stream>>>(Ob, Wot, out, nullptr, nullptr, nullptr, nullptr, nullptr);
}

// Round 12
// 101.480 us; speedup vs baseline: 1.7294x; 1.0085x over previous
//
#include <hip/hip_runtime.h>

typedef unsigned short u16;
typedef unsigned int u32;
typedef short bf16x8 __attribute__((ext_vector_type(8)));
typedef float f32x4 __attribute__((ext_vector_type(4)));
typedef float f32x8v __attribute__((ext_vector_type(8)));
typedef float f32x16 __attribute__((ext_vector_type(16)));

#define LOG2E 1.44269504f

__device__ __forceinline__ u16 f2b(float f) {
  union { float f; unsigned u; } v; v.f = f;
  unsigned r = v.u + 0x7FFFu + ((v.u >> 16) & 1u);
  return (u16)(r >> 16);
}

__device__ __forceinline__ u32 pk2(float a, float b) {
  union { float f; u32 u; } x, y; x.f = a; y.f = b;
  return ((x.u + 0x8000u) >> 16) | ((y.u + 0x8000u) & 0xFFFF0000u);
}

__device__ __forceinline__ u32 cvtpk(float a, float b) {
  u32 r;
  asm("v_cvt_pk_bf16_f32 %0, %1, %2" : "=v"(r) : "v"(a), "v"(b));
  return r;
}

__device__ __forceinline__ float max3f(float a, float b, float c) {
  float r;
  asm("v_max3_f32 %0, %1, %2, %3" : "=v"(r) : "v"(a), "v"(b), "v"(c));
  return r;
}

__device__ __forceinline__ void plswap(u32& x, u32& y) {
#if __has_builtin(__builtin_amdgcn_permlane32_swap)
  typedef int v2i __attribute__((ext_vector_type(2)));
  v2i r = __builtin_amdgcn_permlane32_swap((int)x, (int)y, false, false);
  x = (u32)r[0]; y = (u32)r[1];
#else
  u32 sx = (u32)__shfl_xor((int)x, 32, 64);
  u32 sy = (u32)__shfl_xor((int)y, 32, 64);
  bool hi = (threadIdx.x & 63) >= 32;
  u32 nx = hi ? sy : x;
  u32 ny = hi ? y : sx;
  x = nx; y = ny;
#endif
}

// async global->LDS, 16B per lane; LDS dest is wave-uniform base (HW adds lane*16)
__device__ __forceinline__ void gld16(const void* g, void* l) {
  __builtin_amdgcn_global_load_lds((const __attribute__((address_space(1))) void*)g,
                                   (__attribute__((address_space(3))) void*)l, 16, 0, 0);
}

// inverse of LDS fragment swizzle ba(r,o) = (r*64 + o*16) ^ ((r&7)<<4), L = c*16
__device__ __forceinline__ void invswz(int c, int& r, int& o) {
  int rhalf = c >> 3;
  int r2 = (rhalf >> 1) & 1;
  int r0 = ((c >> 2) & 1) ^ r2;
  r = rhalf * 2 + r0;
  int o0 = (c & 1) ^ r0;
  int o1 = ((c >> 1) & 1) ^ (rhalf & 1);
  o = o0 + 2 * o1;
}

// ------------- prep0: cast x (blk<4096) | transpose w_qkv (<6144) | transpose w_out -------------
__global__ __launch_bounds__(256) void k_prep0(const float* __restrict__ x, u16* __restrict__ Xb,
                                               const float* __restrict__ w_qkv, u16* __restrict__ Wqt,
                                               const float* __restrict__ w_out, u16* __restrict__ Wot) {
  __shared__ float tile[32][33];
  int blk = blockIdx.x;
  int tid = threadIdx.x;
  if (blk < 4096) {
    int i = blk * 256 + tid;
    float4 v = ((const float4*)x)[i];
    ushort4 o;
    o.x = f2b(v.x); o.y = f2b(v.y); o.z = f2b(v.z); o.w = f2b(v.w);
    ((ushort4*)Xb)[i] = o;
    return;
  }
  const float* in; u16* out; int R, C, t;
  if (blk < 6144) { t = blk - 4096; in = w_qkv; out = Wqt; R = 1024; C = 2048; }
  else            { t = blk - 6144; in = w_out; out = Wot; R = 1024; C = 1024; }
  int nbx = C >> 5;
  int c0 = (t % nbx) * 32, r0 = (t / nbx) * 32;
  int tx = tid & 31, ty = tid >> 5;
#pragma unroll
  for (int i = 0; i < 32; i += 8)
    tile[ty + i][tx] = in[(size_t)(r0 + ty + i) * C + c0 + tx];
  __syncthreads();
#pragma unroll
  for (int i = 0; i < 32; i += 8)
    out[(size_t)(c0 + ty + i) * R + r0 + tx] = f2b(tile[tx][ty + i]);
}

// ------------- GEMM: BMx128 tile, global_load_lds staging (pre-swizzled source), dbuf, counted vmcnt
// EPI 0: C fp32 store. EPI 1 (qkv): cols<1536 -> in-register RoPE -> Qb/Kb bf16; else Vb bf16.
template<int BM, int Nsz, int Ksz, int EPI>
__global__ __launch_bounds__(256) void k_gemm(const u16* __restrict__ A, const u16* __restrict__ Bt,
                                              float* __restrict__ C, const float* __restrict__ cs,
                                              const float* __restrict__ sn, u16* __restrict__ Qb,
                                              u16* __restrict__ Kb, u16* __restrict__ Vb) {
  constexpr int MT = BM / 32;       // acc m-tiles per wave
  constexpr int CA = BM / 64;       // A staging calls
  __shared__ u16 As[2][BM * 32];
  __shared__ u16 Bs[2][128 * 32];
  const int tid = threadIdx.x;
  const int l = tid & 63, w = tid >> 6;
  const int wm = w >> 1, wn = w & 1;
  const int m0 = blockIdx.x * BM, n0 = blockIdx.y * 128;
  const int rg = l >> 4, cl = l & 15;

  // staging sources: lane's linear LDS slot c -> (row,off) via inverse swizzle
  const u16* aSrc[2];
  const u16* bSrc[2];
#pragma unroll
  for (int i = 0; i < CA; i++) {
    int r, o; invswz(i * 256 + tid, r, o);
    aSrc[i] = A + (size_t)(m0 + r) * Ksz + o * 8;
  }
#pragma unroll
  for (int i = 0; i < 2; i++) {
    int r, o; invswz(i * 256 + tid, r, o);
    bSrc[i] = Bt + (size_t)(n0 + r) * Ksz + o * 8;
  }

  auto stage = [&](int buf) {
#pragma unroll
    for (int i = 0; i < CA; i++) {
      gld16(aSrc[i], (char*)As + buf * (BM * 64) + i * 4096 + w * 1024);
      aSrc[i] += 32;
    }
#pragma unroll
    for (int i = 0; i < 2; i++) {
      gld16(bSrc[i], (char*)Bs + buf * 8192 + i * 4096 + w * 1024);
      bSrc[i] += 32;
    }
  };

  f32x4 acc[MT][4] = {};
  const int NK = Ksz / 32;
  stage(0);
  for (int j = 0; j < NK; j++) {
    const int cur = j & 1;
    if (j + 1 < NK) {
      stage(cur ^ 1);
      if constexpr (CA == 2) asm volatile("s_waitcnt vmcnt(4)" ::: "memory");
      else                   asm volatile("s_waitcnt vmcnt(3)" ::: "memory");
    } else {
      asm volatile("s_waitcnt vmcnt(0)" ::: "memory");
    }
    __builtin_amdgcn_s_barrier();
    asm volatile("" ::: "memory");

    bf16x8 aF[MT], bF[4];
#pragma unroll
    for (int m = 0; m < MT; m++) {
      int row = wm * (BM / 2) + m * 16 + cl;
      unsigned ba = (unsigned)((row * 64 + rg * 16) ^ ((row & 7) << 4));
      aF[m] = *(const bf16x8*)((char*)As[cur] + ba);
    }
#pragma unroll
    for (int n = 0; n < 4; n++) {
      int row = wn * 64 + n * 16 + cl;
      unsigned ba = (unsigned)((row * 64 + rg * 16) ^ ((row & 7) << 4));
      bF[n] = *(const bf16x8*)((char*)Bs[cur] + ba);
    }
    __builtin_amdgcn_s_setprio(1);
#pragma unroll
    for (int m = 0; m < MT; m++)
#pragma unroll
      for (int n = 0; n < 4; n++)
        acc[m][n] = __builtin_amdgcn_mfma_f32_16x16x32_bf16(aF[m], bF[n], acc[m][n], 0, 0, 0);
    __builtin_amdgcn_s_setprio(0);
    asm volatile("" ::: "memory");
    __builtin_amdgcn_s_barrier();
  }

  if constexpr (EPI == 0) {
#pragma unroll
    for (int m = 0; m < MT; m++)
#pragma unroll
      for (int n = 0; n < 4; n++)
#pragma unroll
        for (int r = 0; r < 4; r++)
          C[(size_t)(m0 + wm * (BM / 2) + m * 16 + rg * 4 + r) * Nsz + n0 + wn * 64 + n * 16 + cl] =
              acc[m][n][r];
  } else {
    const int col0 = n0 + wn * 64;   // 64-aligned -> exactly one head
    if (col0 < 1536) {
      const bool isQ = col0 < 1024;
      const float scale = isQ ? 0.125f : 1.0f;
      u16* dst = isQ ? Qb : Kb;
      const int hh = isQ ? (col0 >> 6) : ((col0 - 1024) >> 6);
      const int HN = isQ ? 16 : 8;
#pragma unroll
      for (int m = 0; m < MT; m++)
#pragma unroll
        for (int r = 0; r < 4; r++) {
          int tg = m0 + wm * (BM / 2) + m * 16 + rg * 4 + r;
          int bb = tg >> 11, tt = tg & 2047;
          size_t base = ((size_t)(bb * HN + hh) * 2048 + tt) * 64;
#pragma unroll
          for (int n = 0; n < 4; n++) {
            int d = n * 16 + cl;
            float cv = cs[tt * 64 + d], sv = sn[tt * 64 + d];
            float partner = acc[m][n ^ 2][r];
            float val = acc[m][n][r] * cv + ((n < 2) ? -partner : partner) * sv;
            dst[base + d] = f2b(val * scale);
          }
        }
    } else {
#pragma unroll
      for (int m = 0; m < MT; m++)
#pragma unroll
        for (int r = 0; r < 4; r++) {
          int tg = m0 + wm * (BM / 2) + m * 16 + rg * 4 + r;
#pragma unroll
          for (int n = 0; n < 4; n++)
            Vb[(size_t)tg * 512 + (col0 - 1536) + n * 16 + cl] = f2b(acc[m][n][r]);
        }
    }
  }
}

// ------------- V transpose: Vb bf16 [4096][512] -> Vt[b*8+kh][64][2048] bf16 -------------
__global__ __launch_bounds__(256) void k_vtrans(const u16* __restrict__ Vb, u16* __restrict__ Vt) {
  __shared__ u16 tile[64][65];
  int blk = blockIdx.x;
  int t0 = (blk & 31) * 64;
  int bh = blk >> 5;  // b*8+kh
  int tx = threadIdx.x & 63, ty = threadIdx.x >> 6;
  const u16* src = Vb + ((size_t)((bh >> 3) * 2048 + t0)) * 512 + (bh & 7) * 64;
#pragma unroll
  for (int i = 0; i < 64; i += 4)
    tile[ty + i][tx] = src[(size_t)(ty + i) * 512 + tx];
  __syncthreads();
  u16* dst = Vt + (size_t)bh * 64 * 2048 + t0;
#pragma unroll
  for (int i = 0; i < 64; i += 4)
    dst[(size_t)(ty + i) * 2048 + tx] = tile[tx][ty + i];
}

// ---- causal flash attention v12: flash10 structure + corrected ONE-barrier-per-tile loop ----
// Ordering per tile: {vmcnt(0) -> barrier -> STAGE(next) -> compute(cur)}.
// Safety: (a) each wave's vmcnt confirms its own staged portion landed BEFORE the barrier,
// so post-barrier the whole tile is visible; (b) STAGE@i writes buf (i+1)&1 whose only
// readers were compute@i-1, finished by all waves before barrier@i in program order.
__global__ __launch_bounds__(256, 4) void k_flash12(const u16* __restrict__ Qb, const u16* __restrict__ Kb,
                                                    const u16* __restrict__ Vt, u16* __restrict__ Ob) {
  __shared__ u16 smem[16384];  // 32KB: 2 streams x [K dbuf 2x4KB | V dbuf 2x4KB]
  const int tid = threadIdx.x;
  const int l = tid & 63, w = tid >> 6;
  const int sid = w >> 1;        // kv stream 0..1
  const int h01 = w & 1;         // head within kh
  const int bid = blockIdx.x;
  const int bkh = bid & 15;
  const int j = bid >> 4, quad = j >> 4, jj = j & 15;
  const int qt = (quad == 0) ? 63 - jj : (quad == 1) ? jj : (quad == 2) ? 47 - jj : 16 + jj;
  const int b = bkh >> 3, kh = bkh & 7;
  const int h = kh * 2 + h01;
  const int q0 = qt * 32;
  const int lq = l & 31, hi = l >> 5;
  const int q = q0 + lq;

  const int cnt = (qt + 2 - sid) >> 1;   // tiles for this stream (t = sid + 2i)
  const int CNTMAX = (qt + 2) >> 1;

  const u16* Kg = Kb + (size_t)(b * 8 + kh) * 2048 * 64;
  const u16* Vg = Vt + (size_t)(b * 8 + kh) * 64 * 2048;
  const u16* Qp = Qb + ((size_t)(b * 16 + h) * 2048 + q) * 64 + hi * 8;

  // ---- hoisted staging pointers, swz(row) = (row ^ (row>>3)) (K: &7 / V: &3 on (d>>1)) ----
  const int krow = h01 * 16 + (l >> 3);
  const int swk1 = (krow ^ (krow >> 3)) & 7;
  const int swk2 = ((krow + 8) ^ ((krow + 8) >> 3)) & 7;
  const u16* kS1 = Kg + (size_t)(sid * 32 + krow) * 64 + (((l & 7) ^ swk1) << 3);
  const u16* kS2 = Kg + (size_t)(sid * 32 + krow + 8) * 64 + (((l & 7) ^ swk2) << 3);
  const int vd = h01 * 32 + (l >> 2);
  const int swv1 = ((vd >> 1) ^ (vd >> 3)) & 3;
  const int swv2 = (((vd + 16) >> 1) ^ ((vd + 16) >> 3)) & 3;
  const u16* vS0 = Vg + (size_t)vd * 2048 + sid * 32 + (((l & 3) ^ swv1) << 3);
  const u16* vS1 = Vg + (size_t)(vd + 16) * 2048 + sid * 32 + (((l & 3) ^ swv2) << 3);
  char* smB = (char*)smem;
  const int kDst = sid * 16384 + h01 * 2048;
  const int vDst = sid * 16384 + 8192 + h01 * 2048;

#define STAGE(buf)                                         \
  {                                                        \
    gld16(kS1, smB + kDst + (buf) * 4096);                 \
    gld16(kS2, smB + kDst + (buf) * 4096 + 1024);          \
    gld16(vS0, smB + vDst + (buf) * 4096);                 \
    gld16(vS1, smB + vDst + (buf) * 4096 + 1024);          \
    kS1 += 4096; kS2 += 4096; vS0 += 64; vS1 += 64;        \
  }

  if (cnt > 0) STAGE(0);

  bf16x8 qf[4];
#pragma unroll
  for (int ks = 0; ks < 4; ks++) qf[ks] = *(const bf16x8*)(Qp + ks * 16);

  union { u32 uu[4]; bf16x8 v; } ones;
#pragma unroll
  for (int jo = 0; jo < 4; jo++) ones.uu[jo] = 0x3F803F80u;

  f32x16 oa[2] = {};
  f32x16 lacc = {};
  float m = -3e38f;
  const int swzkr = (lq ^ (lq >> 3)) & 7;
  const int swzvr = ((lq >> 1) ^ (lq >> 3)) & 3;

  for (int i = 0; i < CNTMAX; i++) {
    const int cur = i & 1;
    // one barrier per tile: own loads landed -> publish -> stage next -> compute current
    asm volatile("s_waitcnt vmcnt(0)" ::: "memory");
    __builtin_amdgcn_s_barrier();
    asm volatile("" ::: "memory");
    if (i + 1 < cnt) STAGE(cur ^ 1);

    if (i < cnt) {
      const int t = sid + 2 * i;
      const char* KL = smB + sid * 16384 + cur * 4096;
      const char* VL = smB + sid * 16384 + 8192 + cur * 4096;

      bf16x8 kf[4];
#pragma unroll
      for (int ks = 0; ks < 4; ks++)
        kf[ks] = *(const bf16x8*)(KL + lq * 128 + ((((ks << 1) | hi) ^ swzkr) << 4));
      f32x16 s0 = {};
      __builtin_amdgcn_s_setprio(1);
#pragma unroll
      for (int ks = 0; ks < 4; ks++)
        s0 = __builtin_amdgcn_mfma_f32_32x32x16_bf16(kf[ks], qf[ks], s0, 0, 0, 0);
      __builtin_amdgcn_s_setprio(0);

      if (t == qt) {
#pragma unroll
        for (int r = 0; r < 16; r++) {
          int kvr = (t << 5) + (r & 3) + 8 * (r >> 2) + 4 * hi;
          if (kvr > q) s0[r] = -3e38f;
        }
      }

      float a5[5];
#pragma unroll
      for (int jo = 0; jo < 5; jo++) a5[jo] = max3f(s0[3 * jo], s0[3 * jo + 1], s0[3 * jo + 2]);
      float mx16 = fmaxf(max3f(a5[0], a5[1], a5[2]), max3f(a5[3], a5[4], s0[15]));
      bool keep = __all(mx16 - m <= 8.f);
      if (!keep) {
        float mx = fmaxf(mx16, __shfl_xor(mx16, 32, 64));
        float mnew = fmaxf(m, mx);
        float alpha = exp2f((m - mnew) * LOG2E);
        m = mnew;
        lacc[0] *= alpha;
#pragma unroll
        for (int r = 0; r < 16; r++) { oa[0][r] *= alpha; oa[1][r] *= alpha; }
      }
      float mb = m * LOG2E;
#pragma unroll
      for (int r = 0; r < 16; r++) s0[r] = exp2f(fmaf(s0[r], LOG2E, -mb));

      u32 aw[8];
#pragma unroll
      for (int jo = 0; jo < 8; jo++) aw[jo] = cvtpk(s0[2 * jo], s0[2 * jo + 1]);
      plswap(aw[0], aw[2]); plswap(aw[1], aw[3]);
      plswap(aw[4], aw[6]); plswap(aw[5], aw[7]);
      union { u32 uu[4]; bf16x8 v; } p0, p1;
#pragma unroll
      for (int jo = 0; jo < 4; jo++) { p0.uu[jo] = aw[jo]; p1.uu[jo] = aw[4 + jo]; }

      bf16x8 vf[2][2];
#pragma unroll
      for (int dt = 0; dt < 2; dt++)
#pragma unroll
        for (int p = 0; p < 2; p++)
          vf[dt][p] = *(const bf16x8*)(VL + (dt * 32 + lq) * 64 + ((((p << 1) | hi) ^ swzvr) << 4));

      __builtin_amdgcn_s_setprio(1);
#pragma unroll
      for (int dt = 0; dt < 2; dt++) {
        oa[dt] = __builtin_amdgcn_mfma_f32_32x32x16_bf16(vf[dt][0], p0.v, oa[dt], 0, 0, 0);
        oa[dt] = __builtin_amdgcn_mfma_f32_32x32x16_bf16(vf[dt][1], p1.v, oa[dt], 0, 0, 0);
      }
      lacc = __builtin_amdgcn_mfma_f32_32x32x16_bf16(ones.v, p0.v, lacc, 0, 0, 0);
      lacc = __builtin_amdgcn_mfma_f32_32x32x16_bf16(ones.v, p1.v, lacc, 0, 0, 0);
      __builtin_amdgcn_s_setprio(0);
    }
    asm volatile("" ::: "memory");
  }

  float lsum = lacc[0];

  // ---- 2-way merge per head (overlay staging LDS) ----
  __syncthreads();
  float* pbuf = (float*)smem;                       // [2][64][33] f32
  float* mlb = (float*)((char*)smem + 16896);       // [2][128] f32
  u32* otileB = (u32*)((char*)smem + 17920);        // [2][32*33] u32
  if (sid == 1) {
    float* pb = pbuf + (h01 * 64 + l) * 33;
#pragma unroll
    for (int r = 0; r < 16; r++) { pb[r] = oa[0][r]; pb[16 + r] = oa[1][r]; }
    mlb[h01 * 128 + l] = m;
    mlb[h01 * 128 + 64 + l] = lsum;
  }
  __syncthreads();
  if (sid == 0) {
    float m1 = mlb[h01 * 128 + l], l1 = mlb[h01 * 128 + 64 + l];
    float ms = fmaxf(m, m1);
    float a0 = exp2f((m - ms) * LOG2E);
    float a1 = exp2f((m1 - ms) * LOG2E);
    float linv = 1.0f / (lsum * a0 + l1 * a1);
    a0 *= linv; a1 *= linv;
    const float* pb = pbuf + (h01 * 64 + l) * 33;
    float of[32];
#pragma unroll
    for (int r = 0; r < 16; r++) {
      of[r] = oa[0][r] * a0 + pb[r] * a1;
      of[16 + r] = oa[1][r] * a0 + pb[16 + r] * a1;
    }
    u32* ot = otileB + h01 * (32 * 33);
#pragma unroll
    for (int dt = 0; dt < 2; dt++)
#pragma unroll
      for (int r = 0; r < 16; r += 2) {
        int d = dt * 32 + (r & 3) + 8 * (r >> 2) + 4 * hi;
        ot[lq * 33 + (d >> 1)] = cvtpk(of[dt * 16 + r], of[dt * 16 + r + 1]);
      }
#pragma unroll
    for (int i2 = 0; i2 < 16; i2++) {
      int wd = i2 * 64 + l;
      int row = wd >> 5, col = wd & 31;
      u32 v = ot[row * 33 + col];
      *(u32*)(Ob + (size_t)(b * 2048 + q0 + row) * 1024 + h * 64 + col * 2) = v;
    }
  }
#undef STAGE
}

extern "C" void kernel_launch(void* const* d_in, const int* in_sizes, int n_in,
                              void* d_out, int out_size, void* d_ws, size_t ws_size,
                              hipStream_t stream) {
  const float* x = (const float*)d_in[0];
  const float* cs = (const float*)d_in[1];
  const float* sn = (const float*)d_in[2];
  const float* w_qkv = (const float*)d_in[3];
  const float* w_out = (const float*)d_in[4];
  float* out = (float*)d_out;
  char* ws = (char*)d_ws;

  u16* Xb  = (u16*)(ws);                       // 8 MB  [4096][1024]
  u16* Wqt = (u16*)(ws + ((size_t)8u << 20));  // 4 MB  [2048][1024]
  u16* Wot = (u16*)(ws + ((size_t)12u << 20)); // 2 MB  [1024][1024]
  u16* Vb  = (u16*)(ws + ((size_t)14u << 20)); // 4 MB  [4096][512] bf16
  u16* Qb  = (u16*)(ws + ((size_t)18u << 20)); // 8 MB  [2][16][2048][64]
  u16* Kb  = (u16*)(ws + ((size_t)26u << 20)); // 4 MB  [2][8][2048][64]
  u16* Vt  = (u16*)(ws + ((size_t)30u << 20)); // 4 MB  [2][8][64][2048]
  u16* Ob  = (u16*)(ws + ((size_t)34u << 20)); // 8 MB  [4096][1024]

  k_prep0<<<7168, 256, 0, stream>>>(x, Xb, w_qkv, Wqt, w_out, Wot);
  k_gemm<128, 2048, 1024, 1><<<dim3(32, 16), 256, 0, stream>>>(Xb, Wqt, nullptr, cs, sn, Qb, Kb, Vb);
  k_vtrans<<<512, 256, 0, stream>>>(Vb, Vt);
  k_flash12<<<1024, 256, 0, stream>>>(Qb, Kb, Vt, Ob);
  k_gemm<64, 1024, 1024, 0><<<dim3(64, 8), 256, 0, stream>>>(Ob, Wot, out, nullptr, nullptr, nullptr, nullptr, nullptr);
}

// Round 13
// 101.284 us; speedup vs baseline: 1.7328x; 1.0019x over previous
//
#include <hip/hip_runtime.h>

typedef unsigned short u16;
typedef unsigned int u32;
typedef short bf16x8 __attribute__((ext_vector_type(8)));
typedef float f32x4 __attribute__((ext_vector_type(4)));
typedef float f32x8v __attribute__((ext_vector_type(8)));
typedef float f32x16 __attribute__((ext_vector_type(16)));

#define LOG2E 1.44269504f

__device__ __forceinline__ u16 f2b(float f) {
  union { float f; unsigned u; } v; v.f = f;
  unsigned r = v.u + 0x7FFFu + ((v.u >> 16) & 1u);
  return (u16)(r >> 16);
}

__device__ __forceinline__ u32 pk2(float a, float b) {
  union { float f; u32 u; } x, y; x.f = a; y.f = b;
  return ((x.u + 0x8000u) >> 16) | ((y.u + 0x8000u) & 0xFFFF0000u);
}

__device__ __forceinline__ u32 cvtpk(float a, float b) {
  u32 r;
  asm("v_cvt_pk_bf16_f32 %0, %1, %2" : "=v"(r) : "v"(a), "v"(b));
  return r;
}

__device__ __forceinline__ float max3f(float a, float b, float c) {
  float r;
  asm("v_max3_f32 %0, %1, %2, %3" : "=v"(r) : "v"(a), "v"(b), "v"(c));
  return r;
}

__device__ __forceinline__ void plswap(u32& x, u32& y) {
#if __has_builtin(__builtin_amdgcn_permlane32_swap)
  typedef int v2i __attribute__((ext_vector_type(2)));
  v2i r = __builtin_amdgcn_permlane32_swap((int)x, (int)y, false, false);
  x = (u32)r[0]; y = (u32)r[1];
#else
  u32 sx = (u32)__shfl_xor((int)x, 32, 64);
  u32 sy = (u32)__shfl_xor((int)y, 32, 64);
  bool hi = (threadIdx.x & 63) >= 32;
  u32 nx = hi ? sy : x;
  u32 ny = hi ? y : sx;
  x = nx; y = ny;
#endif
}

// async global->LDS, 16B per lane; LDS dest is wave-uniform base (HW adds lane*16)
__device__ __forceinline__ void gld16(const void* g, void* l) {
  __builtin_amdgcn_global_load_lds((const __attribute__((address_space(1))) void*)g,
                                   (__attribute__((address_space(3))) void*)l, 16, 0, 0);
}

// inverse of LDS fragment swizzle ba(r,o) = (r*64 + o*16) ^ ((r&7)<<4), L = c*16
__device__ __forceinline__ void invswz(int c, int& r, int& o) {
  int rhalf = c >> 3;
  int r2 = (rhalf >> 1) & 1;
  int r0 = ((c >> 2) & 1) ^ r2;
  r = rhalf * 2 + r0;
  int o0 = (c & 1) ^ r0;
  int o1 = ((c >> 1) & 1) ^ (rhalf & 1);
  o = o0 + 2 * o1;
}

// ------------- prep0: cast x (blk<4096) | transpose w_qkv (<6144) | transpose w_out -------------
__global__ __launch_bounds__(256) void k_prep0(const float* __restrict__ x, u16* __restrict__ Xb,
                                               const float* __restrict__ w_qkv, u16* __restrict__ Wqt,
                                               const float* __restrict__ w_out, u16* __restrict__ Wot) {
  __shared__ float tile[32][33];
  int blk = blockIdx.x;
  int tid = threadIdx.x;
  if (blk < 4096) {
    int i = blk * 256 + tid;
    float4 v = ((const float4*)x)[i];
    ushort4 o;
    o.x = f2b(v.x); o.y = f2b(v.y); o.z = f2b(v.z); o.w = f2b(v.w);
    ((ushort4*)Xb)[i] = o;
    return;
  }
  const float* in; u16* out; int R, C, t;
  if (blk < 6144) { t = blk - 4096; in = w_qkv; out = Wqt; R = 1024; C = 2048; }
  else            { t = blk - 6144; in = w_out; out = Wot; R = 1024; C = 1024; }
  int nbx = C >> 5;
  int c0 = (t % nbx) * 32, r0 = (t / nbx) * 32;
  int tx = tid & 31, ty = tid >> 5;
#pragma unroll
  for (int i = 0; i < 32; i += 8)
    tile[ty + i][tx] = in[(size_t)(r0 + ty + i) * C + c0 + tx];
  __syncthreads();
#pragma unroll
  for (int i = 0; i < 32; i += 8)
    out[(size_t)(c0 + ty + i) * R + r0 + tx] = f2b(tile[tx][ty + i]);
}

// ------------- GEMM: BMx128 tile, global_load_lds staging (pre-swizzled source), dbuf, counted vmcnt
// EPI 0: C fp32 store. EPI 1 (qkv): cols<1536 -> in-register RoPE -> Qb/Kb bf16;
//                                   cols>=1536 -> LDS transpose -> Vt[b*8+kh][d][t] bf16 (vtrans fused).
template<int BM, int Nsz, int Ksz, int EPI>
__global__ __launch_bounds__(256) void k_gemm(const u16* __restrict__ A, const u16* __restrict__ Bt,
                                              float* __restrict__ C, const float* __restrict__ cs,
                                              const float* __restrict__ sn, u16* __restrict__ Qb,
                                              u16* __restrict__ Kb, u16* __restrict__ Vt) {
  constexpr int MT = BM / 32;       // acc m-tiles per wave
  constexpr int CA = BM / 64;       // A staging calls
  constexpr int ABytes = BM * 128;  // 2 bufs x BM*32 u16 x 2B
  __shared__ u16 sm[(EPI == 1) ? 16640 : (BM * 64 + 8192)];  // stage bufs; EPI1 epilogue reuses as [128][130]
  const int tid = threadIdx.x;
  const int l = tid & 63, w = tid >> 6;
  const int wm = w >> 1, wn = w & 1;
  const int m0 = blockIdx.x * BM, n0 = blockIdx.y * 128;
  const int rg = l >> 4, cl = l & 15;

  // staging sources: lane's linear LDS slot c -> (row,off) via inverse swizzle
  const u16* aSrc[2];
  const u16* bSrc[2];
#pragma unroll
  for (int i = 0; i < CA; i++) {
    int r, o; invswz(i * 256 + tid, r, o);
    aSrc[i] = A + (size_t)(m0 + r) * Ksz + o * 8;
  }
#pragma unroll
  for (int i = 0; i < 2; i++) {
    int r, o; invswz(i * 256 + tid, r, o);
    bSrc[i] = Bt + (size_t)(n0 + r) * Ksz + o * 8;
  }

  auto stage = [&](int buf) {
#pragma unroll
    for (int i = 0; i < CA; i++) {
      gld16(aSrc[i], (char*)sm + buf * (BM * 64) + i * 4096 + w * 1024);
      aSrc[i] += 32;
    }
#pragma unroll
    for (int i = 0; i < 2; i++) {
      gld16(bSrc[i], (char*)sm + ABytes + buf * 8192 + i * 4096 + w * 1024);
      bSrc[i] += 32;
    }
  };

  f32x4 acc[MT][4] = {};
  const int NK = Ksz / 32;
  stage(0);
  for (int j = 0; j < NK; j++) {
    const int cur = j & 1;
    if (j + 1 < NK) {
      stage(cur ^ 1);
      if constexpr (CA == 2) asm volatile("s_waitcnt vmcnt(4)" ::: "memory");
      else                   asm volatile("s_waitcnt vmcnt(3)" ::: "memory");
    } else {
      asm volatile("s_waitcnt vmcnt(0)" ::: "memory");
    }
    __builtin_amdgcn_s_barrier();
    asm volatile("" ::: "memory");

    bf16x8 aF[MT], bF[4];
#pragma unroll
    for (int m = 0; m < MT; m++) {
      int row = wm * (BM / 2) + m * 16 + cl;
      unsigned ba = (unsigned)((row * 64 + rg * 16) ^ ((row & 7) << 4));
      aF[m] = *(const bf16x8*)((char*)sm + cur * (BM * 64) + ba);
    }
#pragma unroll
    for (int n = 0; n < 4; n++) {
      int row = wn * 64 + n * 16 + cl;
      unsigned ba = (unsigned)((row * 64 + rg * 16) ^ ((row & 7) << 4));
      bF[n] = *(const bf16x8*)((char*)sm + ABytes + cur * 8192 + ba);
    }
    __builtin_amdgcn_s_setprio(1);
#pragma unroll
    for (int m = 0; m < MT; m++)
#pragma unroll
      for (int n = 0; n < 4; n++)
        acc[m][n] = __builtin_amdgcn_mfma_f32_16x16x32_bf16(aF[m], bF[n], acc[m][n], 0, 0, 0);
    __builtin_amdgcn_s_setprio(0);
    asm volatile("" ::: "memory");
    __builtin_amdgcn_s_barrier();
  }

  if constexpr (EPI == 0) {
#pragma unroll
    for (int m = 0; m < MT; m++)
#pragma unroll
      for (int n = 0; n < 4; n++)
#pragma unroll
        for (int r = 0; r < 4; r++)
          C[(size_t)(m0 + wm * (BM / 2) + m * 16 + rg * 4 + r) * Nsz + n0 + wn * 64 + n * 16 + cl] =
              acc[m][n][r];
  } else {
    const int col0 = n0 + wn * 64;   // 64-aligned -> exactly one head; branch is block-uniform (n0 granularity 128)
    if (col0 < 1536) {
      const bool isQ = col0 < 1024;
      const float scale = isQ ? 0.125f : 1.0f;
      u16* dst = isQ ? Qb : Kb;
      const int hh = isQ ? (col0 >> 6) : ((col0 - 1024) >> 6);
      const int HN = isQ ? 16 : 8;
#pragma unroll
      for (int m = 0; m < MT; m++)
#pragma unroll
        for (int r = 0; r < 4; r++) {
          int tg = m0 + wm * (BM / 2) + m * 16 + rg * 4 + r;
          int bb = tg >> 11, tt = tg & 2047;
          size_t base = ((size_t)(bb * HN + hh) * 2048 + tt) * 64;
#pragma unroll
          for (int n = 0; n < 4; n++) {
            int d = n * 16 + cl;
            float cv = cs[tt * 64 + d], sv = sn[tt * 64 + d];
            float partner = acc[m][n ^ 2][r];
            float val = acc[m][n][r] * cv + ((n < 2) ? -partner : partner) * sv;
            dst[base + d] = f2b(val * scale);
          }
        }
    } else {
      // ---- fused V transpose: acc tile (128t x 128d) -> LDS [t][130] -> Vt[d][t] coalesced ----
      __syncthreads();
      u16* tb = sm;
#pragma unroll
      for (int m = 0; m < MT; m++)
#pragma unroll
        for (int r = 0; r < 4; r++) {
          int tr = wm * (BM / 2) + m * 16 + rg * 4 + r;
#pragma unroll
          for (int n = 0; n < 4; n++)
            tb[tr * 130 + wn * 64 + n * 16 + cl] = f2b(acc[m][n][r]);
        }
      __syncthreads();
      const int bb = m0 >> 11, t0 = m0 & 2047;
#pragma unroll
      for (int i = 0; i < 32; i++) {
        int idx = i * 256 + tid;
        int d = idx >> 6, tp = (idx & 63) * 2;
        u32 v = (u32)tb[tp * 130 + d] | ((u32)tb[(tp + 1) * 130 + d] << 16);
        int dcol = n0 - 1536 + d;
        *(u32*)(Vt + (((size_t)(bb * 8) + (dcol >> 6)) * 64 + (dcol & 63)) * 2048 + t0 + tp) = v;
      }
    }
  }
}

// ---- causal flash attention v13: flash12 + mapping-robust interleaved qt assignment ----
// qt = (j&1) ? 63-(j>>1) : (j>>1): any contiguous even-width window of j sums to ~63*w/2,
// so per-SIMD resident work is ~uniform (67 steps) under bid%8->XCD + sequential-in-XCD mapping.
__global__ __launch_bounds__(256, 4) void k_flash13(const u16* __restrict__ Qb, const u16* __restrict__ Kb,
                                                    const u16* __restrict__ Vt, u16* __restrict__ Ob) {
  __shared__ u16 smem[16384];  // 32KB: 2 streams x [K dbuf 2x4KB | V dbuf 2x4KB]
  const int tid = threadIdx.x;
  const int l = tid & 63, w = tid >> 6;
  const int sid = w >> 1;        // kv stream 0..1
  const int h01 = w & 1;         // head within kh
  const int bid = blockIdx.x;
  const int bkh = bid & 15;
  const int j = bid >> 4;
  const int qt = (j & 1) ? (63 - (j >> 1)) : (j >> 1);
  const int b = bkh >> 3, kh = bkh & 7;
  const int h = kh * 2 + h01;
  const int q0 = qt * 32;
  const int lq = l & 31, hi = l >> 5;
  const int q = q0 + lq;

  const int cnt = (qt + 2 - sid) >> 1;   // tiles for this stream (t = sid + 2i)
  const int CNTMAX = (qt + 2) >> 1;

  const u16* Kg = Kb + (size_t)(b * 8 + kh) * 2048 * 64;
  const u16* Vg = Vt + (size_t)(b * 8 + kh) * 64 * 2048;
  const u16* Qp = Qb + ((size_t)(b * 16 + h) * 2048 + q) * 64 + hi * 8;

  // ---- hoisted staging pointers, swz(row) = (row ^ (row>>3)) (K: &7 / V: &3 on (d>>1)) ----
  const int krow = h01 * 16 + (l >> 3);
  const int swk1 = (krow ^ (krow >> 3)) & 7;
  const int swk2 = ((krow + 8) ^ ((krow + 8) >> 3)) & 7;
  const u16* kS1 = Kg + (size_t)(sid * 32 + krow) * 64 + (((l & 7) ^ swk1) << 3);
  const u16* kS2 = Kg + (size_t)(sid * 32 + krow + 8) * 64 + (((l & 7) ^ swk2) << 3);
  const int vd = h01 * 32 + (l >> 2);
  const int swv1 = ((vd >> 1) ^ (vd >> 3)) & 3;
  const int swv2 = (((vd + 16) >> 1) ^ ((vd + 16) >> 3)) & 3;
  const u16* vS0 = Vg + (size_t)vd * 2048 + sid * 32 + (((l & 3) ^ swv1) << 3);
  const u16* vS1 = Vg + (size_t)(vd + 16) * 2048 + sid * 32 + (((l & 3) ^ swv2) << 3);
  char* smB = (char*)smem;
  const int kDst = sid * 16384 + h01 * 2048;
  const int vDst = sid * 16384 + 8192 + h01 * 2048;

#define STAGE(buf)                                         \
  {                                                        \
    gld16(kS1, smB + kDst + (buf) * 4096);                 \
    gld16(kS2, smB + kDst + (buf) * 4096 + 1024);          \
    gld16(vS0, smB + vDst + (buf) * 4096);                 \
    gld16(vS1, smB + vDst + (buf) * 4096 + 1024);          \
    kS1 += 4096; kS2 += 4096; vS0 += 64; vS1 += 64;        \
  }

  if (cnt > 0) STAGE(0);

  bf16x8 qf[4];
#pragma unroll
  for (int ks = 0; ks < 4; ks++) qf[ks] = *(const bf16x8*)(Qp + ks * 16);

  union { u32 uu[4]; bf16x8 v; } ones;
#pragma unroll
  for (int jo = 0; jo < 4; jo++) ones.uu[jo] = 0x3F803F80u;

  f32x16 oa[2] = {};
  f32x16 lacc = {};
  float m = -3e38f;
  const int swzkr = (lq ^ (lq >> 3)) & 7;
  const int swzvr = ((lq >> 1) ^ (lq >> 3)) & 3;

  for (int i = 0; i < CNTMAX; i++) {
    const int cur = i & 1;
    // one barrier per tile: own loads landed -> publish -> stage next -> compute current
    asm volatile("s_waitcnt vmcnt(0)" ::: "memory");
    __builtin_amdgcn_s_barrier();
    asm volatile("" ::: "memory");
    if (i + 1 < cnt) STAGE(cur ^ 1);

    if (i < cnt) {
      const int t = sid + 2 * i;
      const char* KL = smB + sid * 16384 + cur * 4096;
      const char* VL = smB + sid * 16384 + 8192 + cur * 4096;

      bf16x8 kf[4];
#pragma unroll
      for (int ks = 0; ks < 4; ks++)
        kf[ks] = *(const bf16x8*)(KL + lq * 128 + ((((ks << 1) | hi) ^ swzkr) << 4));
      f32x16 s0 = {};
      __builtin_amdgcn_s_setprio(1);
#pragma unroll
      for (int ks = 0; ks < 4; ks++)
        s0 = __builtin_amdgcn_mfma_f32_32x32x16_bf16(kf[ks], qf[ks], s0, 0, 0, 0);
      __builtin_amdgcn_s_setprio(0);

      if (t == qt) {
#pragma unroll
        for (int r = 0; r < 16; r++) {
          int kvr = (t << 5) + (r & 3) + 8 * (r >> 2) + 4 * hi;
          if (kvr > q) s0[r] = -3e38f;
        }
      }

      float a5[5];
#pragma unroll
      for (int jo = 0; jo < 5; jo++) a5[jo] = max3f(s0[3 * jo], s0[3 * jo + 1], s0[3 * jo + 2]);
      float mx16 = fmaxf(max3f(a5[0], a5[1], a5[2]), max3f(a5[3], a5[4], s0[15]));
      bool keep = __all(mx16 - m <= 8.f);
      if (!keep) {
        float mx = fmaxf(mx16, __shfl_xor(mx16, 32, 64));
        float mnew = fmaxf(m, mx);
        float alpha = exp2f((m - mnew) * LOG2E);
        m = mnew;
        lacc[0] *= alpha;
#pragma unroll
        for (int r = 0; r < 16; r++) { oa[0][r] *= alpha; oa[1][r] *= alpha; }
      }
      float mb = m * LOG2E;
#pragma unroll
      for (int r = 0; r < 16; r++) s0[r] = exp2f(fmaf(s0[r], LOG2E, -mb));

      u32 aw[8];
#pragma unroll
      for (int jo = 0; jo < 8; jo++) aw[jo] = cvtpk(s0[2 * jo], s0[2 * jo + 1]);
      plswap(aw[0], aw[2]); plswap(aw[1], aw[3]);
      plswap(aw[4], aw[6]); plswap(aw[5], aw[7]);
      union { u32 uu[4]; bf16x8 v; } p0, p1;
#pragma unroll
      for (int jo = 0; jo < 4; jo++) { p0.uu[jo] = aw[jo]; p1.uu[jo] = aw[4 + jo]; }

      bf16x8 vf[2][2];
#pragma unroll
      for (int dt = 0; dt < 2; dt++)
#pragma unroll
        for (int p = 0; p < 2; p++)
          vf[dt][p] = *(const bf16x8*)(VL + (dt * 32 + lq) * 64 + ((((p << 1) | hi) ^ swzvr) << 4));

      __builtin_amdgcn_s_setprio(1);
#pragma unroll
      for (int dt = 0; dt < 2; dt++) {
        oa[dt] = __builtin_amdgcn_mfma_f32_32x32x16_bf16(vf[dt][0], p0.v, oa[dt], 0, 0, 0);
        oa[dt] = __builtin_amdgcn_mfma_f32_32x32x16_bf16(vf[dt][1], p1.v, oa[dt], 0, 0, 0);
      }
      lacc = __builtin_amdgcn_mfma_f32_32x32x16_bf16(ones.v, p0.v, lacc, 0, 0, 0);
      lacc = __builtin_amdgcn_mfma_f32_32x32x16_bf16(ones.v, p1.v, lacc, 0, 0, 0);
      __builtin_amdgcn_s_setprio(0);
    }
    asm volatile("" ::: "memory");
  }

  float lsum = lacc[0];

  // ---- 2-way merge per head (overlay staging LDS) ----
  __syncthreads();
  float* pbuf = (float*)smem;                       // [2][64][33] f32
  float* mlb = (float*)((char*)smem + 16896);       // [2][128] f32
  u32* otileB = (u32*)((char*)smem + 17920);        // [2][32*33] u32
  if (sid == 1) {
    float* pb = pbuf + (h01 * 64 + l) * 33;
#pragma unroll
    for (int r = 0; r < 16; r++) { pb[r] = oa[0][r]; pb[16 + r] = oa[1][r]; }
    mlb[h01 * 128 + l] = m;
    mlb[h01 * 128 + 64 + l] = lsum;
  }
  __syncthreads();
  if (sid == 0) {
    float m1 = mlb[h01 * 128 + l], l1 = mlb[h01 * 128 + 64 + l];
    float ms = fmaxf(m, m1);
    float a0 = exp2f((m - ms) * LOG2E);
    float a1 = exp2f((m1 - ms) * LOG2E);
    float linv = 1.0f / (lsum * a0 + l1 * a1);
    a0 *= linv; a1 *= linv;
    const float* pb = pbuf + (h01 * 64 + l) * 33;
    float of[32];
#pragma unroll
    for (int r = 0; r < 16; r++) {
      of[r] = oa[0][r] * a0 + pb[r] * a1;
      of[16 + r] = oa[1][r] * a0 + pb[16 + r] * a1;
    }
    u32* ot = otileB + h01 * (32 * 33);
#pragma unroll
    for (int dt = 0; dt < 2; dt++)
#pragma unroll
      for (int r = 0; r < 16; r += 2) {
        int d = dt * 32 + (r & 3) + 8 * (r >> 2) + 4 * hi;
        ot[lq * 33 + (d >> 1)] = cvtpk(of[dt * 16 + r], of[dt * 16 + r + 1]);
      }
#pragma unroll
    for (int i2 = 0; i2 < 16; i2++) {
      int wd = i2 * 64 + l;
      int row = wd >> 5, col = wd & 31;
      u32 v = ot[row * 33 + col];
      *(u32*)(Ob + (size_t)(b * 2048 + q0 + row) * 1024 + h * 64 + col * 2) = v;
    }
  }
#undef STAGE
}

extern "C" void kernel_launch(void* const* d_in, const int* in_sizes, int n_in,
                              void* d_out, int out_size, void* d_ws, size_t ws_size,
                              hipStream_t stream) {
  const float* x = (const float*)d_in[0];
  const float* cs = (const float*)d_in[1];
  const float* sn = (const float*)d_in[2];
  const float* w_qkv = (const float*)d_in[3];
  const float* w_out = (const float*)d_in[4];
  float* out = (float*)d_out;
  char* ws = (char*)d_ws;

  u16* Xb  = (u16*)(ws);                       // 8 MB  [4096][1024]
  u16* Wqt = (u16*)(ws + ((size_t)8u << 20));  // 4 MB  [2048][1024]
  u16* Wot = (u16*)(ws + ((size_t)12u << 20)); // 2 MB  [1024][1024]
  u16* Qb  = (u16*)(ws + ((size_t)18u << 20)); // 8 MB  [2][16][2048][64]
  u16* Kb  = (u16*)(ws + ((size_t)26u << 20)); // 4 MB  [2][8][2048][64]
  u16* Vt  = (u16*)(ws + ((size_t)30u << 20)); // 4 MB  [2][8][64][2048]
  u16* Ob  = (u16*)(ws + ((size_t)34u << 20)); // 8 MB  [4096][1024]

  k_prep0<<<7168, 256, 0, stream>>>(x, Xb, w_qkv, Wqt, w_out, Wot);
  k_gemm<128, 2048, 1024, 1><<<dim3(32, 16), 256, 0, stream>>>(Xb, Wqt, nullptr, cs, sn, Qb, Kb, Vt);
  k_flash13<<<1024, 256, 0, stream>>>(Qb, Kb, Vt, Ob);
  k_gemm<64, 1024, 1024, 0><<<dim3(64, 8), 256, 0, stream>>>(Ob, Wot, out, nullptr, nullptr, nullptr, nullptr, nullptr);
}